// Round 19
// baseline (390.658 us; speedup 1.0000x reference)
//
#include <hip/hip_runtime.h>
#include <hip/hip_bf16.h>

#define NA 4096
#define NP 49152

typedef _Float16 f16;
typedef _Float16 h2 __attribute__((ext_vector_type(2)));
union U4H { uint4 u; f16 h[8]; h2 p[4]; };

__device__ __forceinline__ float fdot2(h2 a, h2 b, float c){
#if __has_builtin(__builtin_amdgcn_fdot2)
  return __builtin_amdgcn_fdot2(a, b, c, false);
#else
  return c + (float)a.x*(float)b.x + (float)a.y*(float)b.y;
#endif
}

// ---------------- ws layout (float-element offsets) ----------------
constexpr int WS_AOFS9 = 64;                   // 32 ints
constexpr int WS_ATTW9 = 128;                  // 512 floats
constexpr int WS_ATTIJ9= WS_ATTW9 + 512;       // 512 ints
constexpr int WS_G     = 12800;                // 5625 Gaunt tensor
constexpr int WS_NATT  = WS_G + 5632;          // int
constexpr int WS_ATTW  = WS_NATT + 8;          // 1024 floats
constexpr int WS_ATTIJ = WS_ATTW + 1024;       // 1024 ints (sorted by k, i-major)
constexpr int WS_TDOFS = WS_ATTIJ + 1024;      // 16 ints
constexpr int WS_TDW   = WS_TDOFS + 16;        // 512 floats
constexpr int WS_TDIJ  = WS_TDW + 512;         // 512 ints
constexpr int WS_AOFS  = WS_TDIJ + 512;        // 32 ints
constexpr int WS_SH    = WS_AOFS + 32;         // NP*9  (SORTED index)
constexpr int WS_RB    = WS_SH + NP*9;         // NP*16 (SORTED index)
constexpr int WS_S     = WS_RB + NP*16;        // NP scores (sorted index)
constexpr int WS_CCNT  = WS_S + NP;            // NA ints
constexpr int WS_COFF  = WS_CCNT + NA;         // NA+1 ints
constexpr int WS_CCUR  = WS_COFF + NA + 8;     // NA ints
constexpr int WS_CLST  = WS_CCUR + NA;         // (unused, kept for layout)
constexpr int WS_XQ    = WS_CLST + NP;         // f16 transposed q (NA*800 halves)
constexpr int WS_XK    = WS_XQ + NA*400;
constexpr int WS_XV    = WS_XK + NA*400;
constexpr int WS_PVF   = WS_XV + NA*400;       // f16: td [sp][g][16]; att [sp][400h]
constexpr int WS_WW    = WS_PVF + NP*128;      // 145920 floats (dead after k_td)
constexpr int WS_PVFE  = WS_PVF + NP*256;
constexpr int WS_DS    = WS_PVFE;              // 2*NP ints: [2*sp]=dst, [2*sp+1]=src
constexpr long long WS_END = (long long)WS_DS + 2*NP + 16;  // ~76 MB

__device__ const float  GLX[16] = {
  -0.98940093499164993f, -0.94457502307323258f, -0.86563120238783174f, -0.75540440835500303f,
  -0.61787624440264375f, -0.45801677765722739f, -0.28160355077925891f, -0.09501250983763744f,
   0.09501250983763744f,  0.28160355077925891f,  0.45801677765722739f,  0.61787624440264375f,
   0.75540440835500303f,  0.86563120238783174f,  0.94457502307323258f,  0.98940093499164993f };
__device__ const double GLW[16] = {
  0.02715245941175409, 0.06225352393864789, 0.09515851168249278, 0.12462897125553387,
  0.14959598881657673, 0.16915651939500254, 0.18260341504492359, 0.18945061045506850,
  0.18945061045506850, 0.18260341504492359, 0.16915651939500254, 0.14959598881657673,
  0.12462897125553387, 0.09515851168249278, 0.06225352393864789, 0.02715245941175409 };

#define PI_D 3.14159265358979323846

__device__ __forceinline__ float scrub(float v){
  if(!(v == v)) return 0.f;
  return fminf(fmaxf(v, -1e30f), 1e30f);
}

__device__ void real_sph25(float ct, float phi, float* Y){
  float st = sqrtf(fmaxf(0.f, 1.f - ct*ct));
  float P[5][5];
  P[0][0] = 1.f;
  #pragma unroll
  for(int m=1;m<=4;m++) P[m][m] = -(2.f*m - 1.f)*st*P[m-1][m-1];
  #pragma unroll
  for(int m=0;m<4;m++) P[m+1][m] = (2.f*m + 1.f)*ct*P[m][m];
  #pragma unroll
  for(int m=0;m<=4;m++){
    #pragma unroll
    for(int l=m+2;l<=4;l++)
      P[l][m] = ((2.f*l - 1.f)*ct*P[l-1][m] - (float)(l+m-1)*P[l-2][m]) / (float)(l-m);
  }
  const double fact[9] = {1,1,2,6,24,120,720,5040,40320};
  int idx = 0;
  #pragma unroll
  for(int l=0;l<=4;l++){
    #pragma unroll
    for(int m=-l;m<=l;m++){
      int ma = (m < 0) ? -m : m;
      float Nn = (float)sqrt((2*l+1)/(4.0*PI_D)*fact[l-ma]/fact[l+ma]);
      float cs = (ma & 1) ? -1.f : 1.f;
      float v;
      if(m == 0)      v = Nn * P[l][0];
      else if(m > 0)  v = 1.4142135623730951f * Nn * cs * cosf(ma*phi) * P[l][ma];
      else            v = 1.4142135623730951f * Nn * cs * sinf(ma*phi) * P[l][ma];
      Y[idx++] = v;
    }
  }
}

// ---------------- u1: {quadrature G | WW prefold | CSR count} --------------
__global__ __launch_bounds__(256) void k_u1(const float* Wrad, const float* W1,
    const float* W2, const int* nbr, float* ws){
  __shared__ float Ysh[12800];
  int b = blockIdx.x, tid = threadIdx.x;
  if(b < 176){
    for(int pt=tid; pt<512; pt+=256){
      float ct  = GLX[pt >> 5];
      float phi = (float)((pt & 31) * (2.0*PI_D/32.0));
      float Y[25];
      real_sph25(ct, phi, Y);
      #pragma unroll
      for(int i=0;i<25;i++) Ysh[pt*25 + i] = Y[i];
    }
    __syncthreads();
    int idx = b*256 + tid;
    int t = idx >> 3, chunk = idx & 7;
    if(t >= 5625) return;
    int k = t % 25, j = (t/25) % 9, i = t/225;
    double acc = 0.0;
    int g0 = chunk*64;
    #pragma unroll 4
    for(int g=g0; g<g0+64; g++){
      double w = GLW[g >> 5] * (2.0*PI_D/32.0);
      acc += w * (double)Ysh[g*25+i] * (double)Ysh[g*25+j] * (double)Ysh[g*25+k];
    }
    acc += __shfl_xor(acc, 1, 8);
    acc += __shfl_xor(acc, 2, 8);
    acc += __shfl_xor(acc, 4, 8);
    if(chunk == 0){
      if(fabs(acc) < 1e-6) acc = 0.0;
      ws[WS_G + (i*9+j)*25 + k] = (float)acc;
    }
  } else if(b < 271){
    int s = b - 176;
    #pragma unroll
    for(int it=0; it<6; it++){
      int idx = tid + 256*it;
      int w = idx / 768, r = idx % 768;
      int d = r / 256, r2 = r % 256, k = r2 / 16, g = r2 % 16;
      const float* Wsrc = (w == 0) ? W1 : W2;
      float acc = 0.f;
      #pragma unroll
      for(int fp=0; fp<16; fp++)
        acc += Wrad[(s*16+k)*16+fp] * Wsrc[(d*16+fp)*16+g];
      ws[WS_WW + ((size_t)(s*2+w)*16 + g)*48 + d*16 + k] = acc;
    }
  } else {
    int p = (b-271)*256 + tid;
    if(p < NP) atomicAdd((int*)ws + WS_CCNT + nbr[2*p], 1);
  }
}

// shfl-based scan: 2 barriers instead of 20
__global__ __launch_bounds__(1024) void k_scan(float* ws){
  __shared__ int wsum[17];
  int t = threadIdx.x;
  const int* cnt = (const int*)ws + WS_CCNT;
  int v0 = cnt[4*t], v1 = cnt[4*t+1], v2 = cnt[4*t+2], v3 = cnt[4*t+3];
  int s = v0+v1+v2+v3;
  int lane = t & 63, w = t >> 6;
  int x = s;
  #pragma unroll
  for(int o=1;o<64;o<<=1){
    int y = __shfl_up(x, o);
    if(lane >= o) x += y;
  }
  if(lane == 63) wsum[w] = x;
  __syncthreads();
  if(t == 0){
    int run = 0;
    #pragma unroll
    for(int i=0;i<16;i++){ int tmp = wsum[i]; wsum[i] = run; run += tmp; }
    wsum[16] = run;
  }
  __syncthreads();
  int base = wsum[w] + x - s;   // exclusive prefix of this thread's 4-group
  int* offp = (int*)ws + WS_COFF;
  int* cur  = (int*)ws + WS_CCUR;
  offp[4*t]   = base;          cur[4*t]   = base;
  offp[4*t+1] = base+v0;       cur[4*t+1] = base+v0;
  offp[4*t+2] = base+v0+v1;    cur[4*t+2] = base+v0+v1;
  offp[4*t+3] = base+v0+v1+v2; cur[4*t+3] = base+v0+v1+v2;
  if(t == 1023) offp[4096] = wsum[16];
}

// ---------------- u2: {Gaunt lists (block 0) | fused fill+pair} ------------
__global__ __launch_bounds__(256) void k_u2(const float* disp, const int* nbr, float* ws){
  __shared__ float Gsh[5632];
  __shared__ int cA[25], cT[9], cA9[25], oA[26], oT[10], oA9[26];
  if(blockIdx.x == 0){
    int t = threadIdx.x;
    for(int i=t; i<5625; i+=256) Gsh[i] = ws[WS_G + i];
    __syncthreads();
    const float* G = Gsh;
    if(t < 25){
      int c=0, c9=0;
      for(int i=0;i<25;i++) for(int j=0;j<9;j++) if(G[(i*9+j)*25+t] != 0.f){ c++; if(i<9) c9++; }
      cA[t]=c; cA9[t]=c9;
    }
    if(t < 9){ int c=0; for(int i=0;i<9;i++) for(int j=0;j<9;j++) if(G[(i*9+j)*25+t] != 0.f) c++; cT[t]=c; }
    __syncthreads();
    if(t == 0){
      int s=0; for(int k=0;k<25;k++){ oA[k]=s; s+=cA[k]; } oA[25]=s;
      ((int*)ws)[WS_NATT] = s;
      s=0; for(int k=0;k<25;k++){ oA9[k]=s; s+=cA9[k]; } oA9[25]=s;
      s=0; for(int k=0;k<9;k++){ oT[k]=s; s+=cT[k]; } oT[9]=s;
    }
    __syncthreads();
    float* attw = ws + WS_ATTW;  int* attij = (int*)ws + WS_ATTIJ;
    float* attw9 = ws + WS_ATTW9; int* attij9 = (int*)ws + WS_ATTIJ9;
    int* aofs  = (int*)ws + WS_AOFS;
    int* aofs9 = (int*)ws + WS_AOFS9;
    if(t < 26){ aofs[t] = oA[t] < 1024 ? oA[t] : 1024; aofs9[t] = oA9[t] < 512 ? oA9[t] : 512; }
    if(t < 25){
      int pos = oA[t], pos9 = oA9[t];
      for(int i=0;i<25;i++) for(int j=0;j<9;j++){
        float w = G[(i*9+j)*25+t];
        if(w != 0.f){
          if(pos < 1024){ attw[pos]=w; attij[pos] = i | (j<<5) | (t<<9); pos++; }
          if(i < 9 && pos9 < 512){ attw9[pos9]=w; attij9[pos9] = i | (j<<5) | (t<<9); pos9++; }
        }
      }
    }
    float* tdw = ws + WS_TDW; int* tdij = (int*)ws + WS_TDIJ; int* tdofs = (int*)ws + WS_TDOFS;
    if(t < 9){
      int pos = oT[t];
      for(int i=0;i<9;i++) for(int j=0;j<9;j++){
        float w = G[(i*9+j)*25+t];
        if(w != 0.f && pos < 512){
          int li = (i==0)?0:(i<4)?1:2, lj = (j==0)?0:(j<4)?1:2;
          tdw[pos]=w; tdij[pos] = i | (j<<5) | (li<<10) | (lj<<12); pos++;
        }
      }
      tdofs[t] = oT[t];
      if(t == 0) tdofs[9] = oT[9];
    }
  } else {
    int p = (blockIdx.x-1)*256 + threadIdx.x;
    if(p >= NP) return;
    int d = nbr[2*p], s = nbr[2*p+1];
    int sp = atomicAdd((int*)ws + WS_CCUR + d, 1);
    ((int*)ws)[WS_DS + 2*sp]     = d;
    ((int*)ws)[WS_DS + 2*sp + 1] = s;
    float dx = disp[3*p], dy = disp[3*p+1], dz = disp[3*p+2];
    float r = sqrtf(dx*dx + dy*dy + dz*dz);
    float inv = 1.f / fmaxf(r, 1e-9f);
    float ux = dx*inv, uy = dy*inv, uz = dz*inv;
    float sh[9];
    sh[0] = 0.28209479177387814f;
    sh[1] = 0.4886025119029199f * uy;
    sh[2] = 0.4886025119029199f * uz;
    sh[3] = 0.4886025119029199f * ux;
    sh[4] = 1.0925484305920792f * ux*uy;
    sh[5] = 1.0925484305920792f * uy*uz;
    sh[6] = 0.31539156525252005f * (3.f*uz*uz - 1.f);
    sh[7] = 1.0925484305920792f * ux*uz;
    sh[8] = 0.5462742152960396f * (ux*ux - uy*uy);
    #pragma unroll
    for(int i=0;i<9;i++) ws[WS_SH + sp*9 + i] = scrub(sh[i]);
    float mask = (r < 5.f) ? 1.f : 0.f;
    float rbv[16];
    #pragma unroll
    for(int k=1;k<=16;k++){
      float x  = (float)k * r * 0.2f;
      float px = 3.14159265358979323846f * x;
      float s2 = (px < 1e-6f) ? 1.f : (sinf(px)/px);
      rbv[k-1] = scrub(s2 * mask);
    }
    float4* rb4 = (float4*)(ws + WS_RB + sp*16);
    #pragma unroll
    for(int c=0;c<4;c++) rb4[c] = make_float4(rbv[4*c], rbv[4*c+1], rbv[4*c+2], rbv[4*c+3]);
  }
}

// ---------------- TD phase (sorted-index reads, W3 staged in LDS) ----------
__global__ __launch_bounds__(256) void k_td(const int* aZ, const float* W3, float* ws){
  __shared__ float sh_s[16][9];
  __shared__ float S_s[16][88];
  __shared__ float tp_s[16][9][16];
  __shared__ float w3_sh[768];
  int tid = threadIdx.x, pl = tid >> 4, g = tid & 15;
  int sp = blockIdx.x*16 + pl;
  int src = ((const int*)ws)[WS_DS + 2*sp + 1];
  int Zj = aZ[src];
  {
    float4* S4 = (float4*)&S_s[0][0];
    for(int t0=tid; t0<352; t0+=256) S4[t0] = make_float4(0.f,0.f,0.f,0.f);
  }
  for(int t0=tid; t0<768; t0+=256) w3_sh[t0] = W3[t0];
  if(g < 9) sh_s[pl][g] = ws[WS_SH + sp*9 + g];
  float rb[16];
  {
    const float4* rb4 = (const float4*)(ws + WS_RB + sp*16);
    #pragma unroll
    for(int c=0;c<4;c++){
      float4 r = rb4[c];
      rb[4*c]=r.x; rb[4*c+1]=r.y; rb[4*c+2]=r.z; rb[4*c+3]=r.w;
    }
  }
  float A1[3], A2[3];
  {
    const float4* w1 = (const float4*)(ws + WS_WW + ((size_t)(Zj*2+0)*16+g)*48);
    const float4* w2 = (const float4*)(ws + WS_WW + ((size_t)(Zj*2+1)*16+g)*48);
    #pragma unroll
    for(int d=0; d<3; d++){
      float a1 = 0.f, a2 = 0.f;
      #pragma unroll
      for(int c=0;c<4;c++){
        float4 x1 = w1[d*4+c], x2 = w2[d*4+c];
        a1 += x1.x*rb[4*c] + x1.y*rb[4*c+1] + x1.z*rb[4*c+2] + x1.w*rb[4*c+3];
        a2 += x2.x*rb[4*c] + x2.y*rb[4*c+1] + x2.z*rb[4*c+2] + x2.w*rb[4*c+3];
      }
      A1[d] = a1; A2[d] = a2;
    }
  }
  __syncthreads();
  if(g < 9){
    const float* tdw = ws + WS_TDW;
    const int* tdij  = (const int*)ws + WS_TDIJ;
    const int* tdofs = (const int*)ws + WS_TDOFS;
    int e1 = tdofs[g+1];
    for(int e=tdofs[g]; e<e1; e++){
      float w = tdw[e]; int meta = tdij[e];
      int i = meta & 31, j = (meta>>5) & 15, li = (meta>>10) & 3, lj = (meta>>12) & 3;
      S_s[pl][g*9 + li*3 + lj] += w * sh_s[pl][i] * sh_s[pl][j];
    }
  }
  __syncthreads();
  float AA[9];
  #pragma unroll
  for(int li=0;li<3;li++)
    #pragma unroll
    for(int lj=0;lj<3;lj++) AA[li*3+lj] = A1[li]*A2[lj];
  #pragma unroll
  for(int k=0;k<9;k++){
    float tpv = 0.f;
    #pragma unroll
    for(int c=0;c<9;c++) tpv += S_s[pl][k*9+c] * AA[c];
    tp_s[pl][k][g] = tpv;
  }
  __syncthreads();
  float acc9[9];
  #pragma unroll
  for(int k=0;k<9;k++){
    int d = (k==0)?0:(k<4)?1:2;
    const float4* t4 = (const float4*)&tp_s[pl][k][0];
    float acc = 0.f;
    #pragma unroll
    for(int c=0;c<4;c++){
      float4 t = t4[c];
      acc += t.x*w3_sh[(d*16+4*c)*16+g]   + t.y*w3_sh[(d*16+4*c+1)*16+g]
           + t.z*w3_sh[(d*16+4*c+2)*16+g] + t.w*w3_sh[(d*16+4*c+3)*16+g];
    }
    acc9[k] = scrub(acc);
  }
  f16* ptd = (f16*)(ws + WS_PVF) + (size_t)sp*256 + g*16;
  U4H u0, u1;
  #pragma unroll
  for(int j=0;j<8;j++) u0.h[j] = (f16)acc9[j];
  u1.h[0] = (f16)acc9[8];
  #pragma unroll
  for(int j=1;j<8;j++) u1.h[j] = (f16)0.f;
  *(uint4*)(ptd)     = u0.u;
  *(uint4*)(ptd + 8) = u1.u;
}

// ---------------- fused TD gather + layer-1 QKV (NL=3) ---------------------
// NOTE: rows 9..15 of q/k/v are ZERO-FILLED (k_att<9> reads i<16 as uint4).
__global__ __launch_bounds__(256) void k_tdq(const float* Wq, const float* Wk,
                                             const float* Wv, float* ws){
  __shared__ float xsh[4][144];
  __shared__ float wq_sh[768], wk_sh[768], wv_sh[768];
  int tid = threadIdx.x, al = tid >> 6, lane = tid & 63;
  int a = blockIdx.x*4 + al;
  for(int t=tid; t<768; t+=256){ wq_sh[t]=Wq[t]; wk_sh[t]=Wk[t]; wv_sh[t]=Wv[t]; }
  const int* coff = (const int*)ws + WS_COFF;
  int off0 = coff[a], n = coff[a+1] - off0;
  const f16* base = (const f16*)(ws + WS_PVF);
  float acc[8] = {0,0,0,0,0,0,0,0}, acc2[8] = {0,0,0,0,0,0,0,0};
  if(lane < 32){
    int t = 0;
    for(; t+1 < n; t += 2){
      U4H u0; u0.u = *(const uint4*)(base + (size_t)(off0+t  )*256 + lane*8);
      U4H u1; u1.u = *(const uint4*)(base + (size_t)(off0+t+1)*256 + lane*8);
      #pragma unroll
      for(int j=0;j<8;j++){ acc[j] += (float)u0.h[j]; acc2[j] += (float)u1.h[j]; }
    }
    if(t < n){
      U4H u0; u0.u = *(const uint4*)(base + (size_t)(off0+t)*256 + lane*8);
      #pragma unroll
      for(int j=0;j<8;j++) acc[j] += (float)u0.h[j];
    }
  }
  float invn = 1.f / fmaxf((float)n, 1.f);
  if(lane < 32){
    int gg = lane >> 1;
    #pragma unroll
    for(int j=0;j<8;j++){
      int k = (lane & 1)*8 + j;
      if(k < 9) xsh[al][k*16 + gg] = scrub((acc[j]+acc2[j])*invn);
    }
  }
  __syncthreads();
  int g = lane & 15, q4 = lane >> 4;
  f16* qt = (f16*)(ws + WS_XQ) + (size_t)a*800 + g*32;
  f16* kt = (f16*)(ws + WS_XK) + (size_t)a*800 + g*32;
  f16* vt = (f16*)(ws + WS_XV) + (size_t)a*800 + g*32;
  for(int i=q4; i<16; i+=4){
    if(i < 9){
      int l = (i==0)?0:(i<4)?1:2;
      float q=0.f, k2=0.f, v2=0.f;
      #pragma unroll
      for(int f2=0;f2<16;f2++){
        float xv = xsh[al][i*16+f2];
        q  += xv*wq_sh[(l*16+f2)*16+g];
        k2 += xv*wk_sh[(l*16+f2)*16+g];
        v2 += xv*wv_sh[(l*16+f2)*16+g];
      }
      qt[i] = (f16)q; kt[i] = (f16)k2; vt[i] = (f16)v2;
    } else {
      qt[i] = (f16)0.f; kt[i] = (f16)0.f; vt[i] = (f16)0.f;
    }
  }
}

// ---------------- merged attention (r12-best: 16 lanes/pair, single chain) -
template<int NI>
__global__ __launch_bounds__(128) void k_att(const float* Wb, float* ws){
  constexpr int MROWH = (NI == 9) ? 16 : 32;
  constexpr int PLSTR = (NI == 9) ? 408 : 840;
  __shared__ __align__(16) f16 Ml[8][PLSTR];
  __shared__ float sh_s[8][9];
  __shared__ float wb_sh[256];
  constexpr int NPAIR = NI/2;
  constexpr int TAIL  = NI-1;
  int tid = threadIdx.x, pl = tid >> 4, g = tid & 15;
  int sp = blockIdx.x*8 + pl;
  {
    uint4 z; z.x=0; z.y=0; z.z=0; z.w=0;
    uint4* Mz = (uint4*)&Ml[0][0];
    for(int t0=tid; t0<PLSTR; t0+=128) Mz[t0] = z;
  }
  for(int t0=tid; t0<256; t0+=128) wb_sh[t0] = Wb[t0];
  if(g < 9) sh_s[pl][g] = ws[WS_SH + sp*9 + g];
  __syncthreads();
  {
    const float* attw = ws + (NI==9 ? WS_ATTW9 : WS_ATTW);
    const int* attij  = (const int*)ws + (NI==9 ? WS_ATTIJ9 : WS_ATTIJ);
    const int* aofs   = (const int*)ws + (NI==9 ? WS_AOFS9 : WS_AOFS);
    for(int kr=g; kr<25; kr+=16){
      f16* Mrow = &Ml[pl][kr*MROWH];
      int e = aofs[kr], e1 = aofs[kr+1];
      if(e < e1){
        int meta = attij[e];
        int curi = meta & 31;
        float cur = 0.f;
        for(; e<e1; e++){
          meta = attij[e];
          int i2 = meta & 31;
          if(i2 != curi){ Mrow[curi] = (f16)cur; cur = 0.f; curi = i2; }
          cur += attw[e] * sh_s[pl][(meta>>5) & 15];
        }
        Mrow[curi] = (f16)cur;
      }
    }
  }
  __syncthreads();
  int dst = ((const int*)ws)[WS_DS + 2*sp];
  int src = ((const int*)ws)[WS_DS + 2*sp + 1];
  float q_r[NI];
  {
    const f16* qt = (const f16*)(ws + WS_XQ) + (size_t)dst*800 + g*32;
    #pragma unroll
    for(int c=0;c<NPAIR/4;c++){
      U4H u; u.u = *(const uint4*)(qt + c*8);
      #pragma unroll
      for(int j=0;j<8;j++) q_r[c*8+j] = (float)u.h[j];
    }
    q_r[TAIL] = (float)qt[TAIL];
  }
  h2 xk2[NPAIR], xv2[NPAIR];
  float xkT, xvT;
  {
    const f16* kt = (const f16*)(ws + WS_XK) + (size_t)src*800 + g*32;
    const f16* vt = (const f16*)(ws + WS_XV) + (size_t)src*800 + g*32;
    #pragma unroll
    for(int c=0;c<NPAIR/4;c++){
      U4H uk; uk.u = *(const uint4*)(kt + c*8);
      U4H uv; uv.u = *(const uint4*)(vt + c*8);
      #pragma unroll
      for(int j=0;j<4;j++){ xk2[c*4+j] = uk.p[j]; xv2[c*4+j] = uv.p[j]; }
    }
    xkT = (float)kt[TAIL];
    xvT = (float)vt[TAIL];
  }
  float wbf;
  {
    const float4* rb4 = (const float4*)(ws + WS_RB + sp*16);
    float acc = 0.f;
    #pragma unroll
    for(int c=0;c<4;c++){
      float4 r = rb4[c];
      acc += r.x*wb_sh[(4*c)*16+g] + r.y*wb_sh[(4*c+1)*16+g]
           + r.z*wb_sh[(4*c+2)*16+g] + r.w*wb_sh[(4*c+3)*16+g];
    }
    wbf = acc;
  }
  f16* pvf = (f16*)(ws + WS_PVF) + (size_t)sp*400;
  float sacc = 0.f;
  #pragma unroll
  for(int k=0;k<25;k++){
    const uint4* Mq = (const uint4*)&Ml[pl][k*MROWH];
    float mT = (float)Ml[pl][k*MROWH + TAIL];
    float vv = 0.f, kf = 0.f;
    #pragma unroll
    for(int c=0;c<NPAIR/4;c++){
      U4H u; u.u = Mq[c];
      #pragma unroll
      for(int j=0;j<4;j++){
        vv = fdot2(u.p[j], xv2[c*4+j], vv);
        if(k < NI) kf = fdot2(u.p[j], xk2[c*4+j], kf);
      }
    }
    vv += mT * xvT;
    if(k < NI){
      kf += mT * xkT;
      sacc += q_r[k]*kf;
    }
    pvf[k*16 + g] = (f16)scrub(wbf*vv);
  }
  float sl = sacc;
  #pragma unroll
  for(int off=1; off<16; off<<=1) sl += __shfl_xor(sl, off, 16);
  if(g == 0) ws[WS_S + sp] = scrub(sl * 0.05f);   // / sqrt(25*16)
}

// ---------------- fused softmax-gather + output pdense (+QKV next / final) -
template<bool FINAL>
__global__ __launch_bounds__(256) void k_aggo(const float* Wo, const float* bo,
    const int* aZ, const float* emb, const float* Wemb, const float* bemb,
    const float* Wq, const float* Wk, const float* Wv, float* ws, float* out){
  __shared__ float xsh[4][400];
  __shared__ float esh[4][64];
  __shared__ float wo_sh[1280];
  __shared__ float wq_sh[FINAL?4:1280], wk_sh[FINAL?4:1280], wv_sh[FINAL?4:1280];
  __shared__ float osh[FINAL?4:1600];
  int tid = threadIdx.x, al = tid >> 6, lane = tid & 63;
  int a = blockIdx.x*4 + al;
  for(int t=tid; t<1280; t+=256){
    wo_sh[t] = Wo[t];
    if(!FINAL){ wq_sh[t]=Wq[t]; wk_sh[t]=Wk[t]; wv_sh[t]=Wv[t]; }
  }
  const int* coff = (const int*)ws + WS_COFF;
  int off0 = coff[a], n = coff[a+1] - off0;
  float mx = -1e30f;
  for(int t=lane; t<n; t+=64) mx = fmaxf(mx, ws[WS_S + off0 + t]);
  #pragma unroll
  for(int off=1; off<64; off<<=1) mx = fmaxf(mx, __shfl_xor(mx, off));
  float den = 0.f;
  for(int t=lane; t<n; t+=64){
    float e = expf(fminf(ws[WS_S + off0 + t] - mx, 0.f));
    if(t < 64) esh[al][t] = e;      // cache for gather (t==lane on 1st iter)
    den += e;
  }
  #pragma unroll
  for(int off=1; off<64; off<<=1) den += __shfl_xor(den, off);
  float inv_den = 1.f / (den + 1e-9f);
  __syncthreads();                   // publish esh (uniform barrier)
  float acc[8] = {0,0,0,0,0,0,0,0}, acc2[8] = {0,0,0,0,0,0,0,0};
  const f16* base = (const f16*)(ws + WS_PVF);
  int t = 0;
  for(; t+1 < n; t += 2){
    float a0 = (t   < 64 ? esh[al][t]   : expf(fminf(ws[WS_S+off0+t  ]-mx,0.f))) * inv_den;
    float a1 = (t+1 < 64 ? esh[al][t+1] : expf(fminf(ws[WS_S+off0+t+1]-mx,0.f))) * inv_den;
    if(lane < 50){
      U4H u0; u0.u = *(const uint4*)(base + (size_t)(off0+t  )*400 + lane*8);
      U4H u1; u1.u = *(const uint4*)(base + (size_t)(off0+t+1)*400 + lane*8);
      #pragma unroll
      for(int j=0;j<8;j++){ acc[j] += a0*(float)u0.h[j]; acc2[j] += a1*(float)u1.h[j]; }
    }
  }
  if(t < n){
    float a0 = (t < 64 ? esh[al][t] : expf(fminf(ws[WS_S+off0+t]-mx,0.f))) * inv_den;
    if(lane < 50){
      U4H u0; u0.u = *(const uint4*)(base + (size_t)(off0+t)*400 + lane*8);
      #pragma unroll
      for(int j=0;j<8;j++) acc[j] += a0*(float)u0.h[j];
    }
  }
  if(lane < 50){
    #pragma unroll
    for(int j=0;j<8;j++) xsh[al][lane*8 + j] = scrub(acc[j] + acc2[j]);   // flat = k*16+g
  }
  __syncthreads();
  int g = lane & 15, q4 = lane >> 4;
  for(int i=q4; i<25; i+=4){
    int l = (i==0)?0:(i<4)?1:(i<9)?2:(i<16)?3:4;
    float accv = 0.f;
    #pragma unroll
    for(int f2=0;f2<16;f2++) accv += xsh[al][i*16+f2]*wo_sh[(l*16+f2)*16+g];
    if(i == 0){
      accv += bo[g];
      if(FINAL){
        int Z = aZ[a];
        float res = bemb[g];
        #pragma unroll
        for(int e2=0;e2<32;e2++) res += emb[Z*32+e2]*Wemb[e2*16+g];
        accv += res;
      }
    }
    if(FINAL) out[a*400 + i*16 + g] = scrub(accv);
    else      osh[al*400 + i*16 + g] = scrub(accv);
  }
  if(!FINAL){
    __syncthreads();
    f16* qt = (f16*)(ws + WS_XQ) + (size_t)a*800 + g*32;
    f16* kt = (f16*)(ws + WS_XK) + (size_t)a*800 + g*32;
    f16* vt = (f16*)(ws + WS_XV) + (size_t)a*800 + g*32;
    for(int i=q4; i<25; i+=4){
      int l = (i==0)?0:(i<4)?1:(i<9)?2:(i<16)?3:4;
      float q=0.f, k2=0.f, v2=0.f;
      #pragma unroll
      for(int f2=0;f2<16;f2++){
        float xv = osh[al*400 + i*16 + f2];
        q  += xv*wq_sh[(l*16+f2)*16+g];
        k2 += xv*wk_sh[(l*16+f2)*16+g];
        v2 += xv*wv_sh[(l*16+f2)*16+g];
      }
      qt[i] = (f16)q; kt[i] = (f16)k2; vt[i] = (f16)v2;
    }
  }
}

extern "C" void kernel_launch(void* const* d_in, const int* in_sizes, int n_in,
                              void* d_out, int out_size, void* d_ws, size_t ws_size,
                              hipStream_t stream){
  (void)in_sizes; (void)n_in; (void)out_size;
  if(ws_size < (size_t)WS_END * sizeof(float)) return;
  float* ws = (float*)d_ws;
  const int* aZ  = (const int*)d_in[0];
  const int* nbr = (const int*)d_in[1];
  const float* disp = (const float*)d_in[2];
  const float* Wrad = (const float*)d_in[3];
  const float* emb  = (const float*)d_in[4];
  const float* Wemb = (const float*)d_in[5];
  const float* bemb = (const float*)d_in[6];
  const float* W1   = (const float*)d_in[7];
  const float* W2   = (const float*)d_in[8];
  const float* W3   = (const float*)d_in[9];
  const float* Wb1 = (const float*)d_in[10]; const float* Wq1 = (const float*)d_in[11];
  const float* Wk1 = (const float*)d_in[12]; const float* Wv1 = (const float*)d_in[13];
  const float* Wo1 = (const float*)d_in[14]; const float* bo1 = (const float*)d_in[15];
  const float* Wb2 = (const float*)d_in[16]; const float* Wq2 = (const float*)d_in[17];
  const float* Wk2 = (const float*)d_in[18]; const float* Wv2 = (const float*)d_in[19];
  const float* Wo2 = (const float*)d_in[20]; const float* bo2 = (const float*)d_in[21];

  hipMemsetAsync(ws + WS_CCNT, 0, NA*sizeof(int), stream);
  k_u1<<<463,256,0,stream>>>(Wrad, W1, W2, nbr, ws);     // G | WW | CSR-count
  k_scan<<<1,1024,0,stream>>>(ws);
  k_u2<<<193,256,0,stream>>>(disp, nbr, ws);             // lists | fill+pair
  k_td<<<3072,256,0,stream>>>(aZ, W3, ws);
  k_tdq<<<1024,256,0,stream>>>(Wq1, Wk1, Wv1, ws);

  k_att<9><<<6144,128,0,stream>>>(Wb1, ws);
  k_aggo<false><<<1024,256,0,stream>>>(Wo1, bo1, aZ, emb, Wemb, bemb,
                                       Wq2, Wk2, Wv2, ws, nullptr);
  k_att<25><<<6144,128,0,stream>>>(Wb2, ws);
  k_aggo<true><<<1024,256,0,stream>>>(Wo2, bo2, aZ, emb, Wemb, bemb,
                                      nullptr, nullptr, nullptr, ws, (float*)d_out);
}

// Round 20
// 389.409 us; speedup vs baseline: 1.0032x; 1.0032x over previous
//
#include <hip/hip_runtime.h>
#include <hip/hip_bf16.h>

#define NA 4096
#define NP 49152

typedef _Float16 f16;
typedef _Float16 h2 __attribute__((ext_vector_type(2)));
union U4H { uint4 u; f16 h[8]; h2 p[4]; };

__device__ __forceinline__ float fdot2(h2 a, h2 b, float c){
#if __has_builtin(__builtin_amdgcn_fdot2)
  return __builtin_amdgcn_fdot2(a, b, c, false);
#else
  return c + (float)a.x*(float)b.x + (float)a.y*(float)b.y;
#endif
}

// ---------------- ws layout (float-element offsets) ----------------
constexpr int WS_AOFS9 = 64;                   // 32 ints
constexpr int WS_ATTW9 = 128;                  // 512 floats
constexpr int WS_ATTIJ9= WS_ATTW9 + 512;       // 512 ints
constexpr int WS_G     = 12800;                // 5625 Gaunt tensor
constexpr int WS_NATT  = WS_G + 5632;          // int
constexpr int WS_ATTW  = WS_NATT + 8;          // 1024 floats
constexpr int WS_ATTIJ = WS_ATTW + 1024;       // 1024 ints (sorted by k, i-major)
constexpr int WS_TDOFS = WS_ATTIJ + 1024;      // 16 ints
constexpr int WS_TDW   = WS_TDOFS + 16;        // 512 floats
constexpr int WS_TDIJ  = WS_TDW + 512;         // 512 ints
constexpr int WS_AOFS  = WS_TDIJ + 512;        // 32 ints
constexpr int WS_SH    = WS_AOFS + 32;         // NP*9  (SORTED index)
constexpr int WS_RB    = WS_SH + NP*9;         // NP*16 (SORTED index)
constexpr int WS_S     = WS_RB + NP*16;        // NP scores (sorted index)
constexpr int WS_CCNT  = WS_S + NP;            // NA ints
constexpr int WS_COFF  = WS_CCNT + NA;         // NA+1 ints
constexpr int WS_CCUR  = WS_COFF + NA + 8;     // NA ints
constexpr int WS_CLST  = WS_CCUR + NA;         // (unused, kept for layout)
constexpr int WS_XQ    = WS_CLST + NP;         // f16 transposed q (NA*800 halves)
constexpr int WS_XK    = WS_XQ + NA*400;
constexpr int WS_XV    = WS_XK + NA*400;
constexpr int WS_PVF   = WS_XV + NA*400;       // f16: td [sp][g][16]; att [sp][400h]
constexpr int WS_WW    = WS_PVF + NP*128;      // 145920 floats (dead after k_td)
constexpr int WS_PVFE  = WS_PVF + NP*256;
constexpr int WS_DS    = WS_PVFE;              // 2*NP ints: [2*sp]=dst, [2*sp+1]=src
constexpr long long WS_END = (long long)WS_DS + 2*NP + 16;  // ~76 MB

__device__ const float  GLX[16] = {
  -0.98940093499164993f, -0.94457502307323258f, -0.86563120238783174f, -0.75540440835500303f,
  -0.61787624440264375f, -0.45801677765722739f, -0.28160355077925891f, -0.09501250983763744f,
   0.09501250983763744f,  0.28160355077925891f,  0.45801677765722739f,  0.61787624440264375f,
   0.75540440835500303f,  0.86563120238783174f,  0.94457502307323258f,  0.98940093499164993f };
__device__ const double GLW[16] = {
  0.02715245941175409, 0.06225352393864789, 0.09515851168249278, 0.12462897125553387,
  0.14959598881657673, 0.16915651939500254, 0.18260341504492359, 0.18945061045506850,
  0.18945061045506850, 0.18260341504492359, 0.16915651939500254, 0.14959598881657673,
  0.12462897125553387, 0.09515851168249278, 0.06225352393864789, 0.02715245941175409 };

#define PI_D 3.14159265358979323846

__device__ __forceinline__ float scrub(float v){
  if(!(v == v)) return 0.f;
  return fminf(fmaxf(v, -1e30f), 1e30f);
}

__device__ void real_sph25(float ct, float phi, float* Y){
  float st = sqrtf(fmaxf(0.f, 1.f - ct*ct));
  float P[5][5];
  P[0][0] = 1.f;
  #pragma unroll
  for(int m=1;m<=4;m++) P[m][m] = -(2.f*m - 1.f)*st*P[m-1][m-1];
  #pragma unroll
  for(int m=0;m<4;m++) P[m+1][m] = (2.f*m + 1.f)*ct*P[m][m];
  #pragma unroll
  for(int m=0;m<=4;m++){
    #pragma unroll
    for(int l=m+2;l<=4;l++)
      P[l][m] = ((2.f*l - 1.f)*ct*P[l-1][m] - (float)(l+m-1)*P[l-2][m]) / (float)(l-m);
  }
  const double fact[9] = {1,1,2,6,24,120,720,5040,40320};
  int idx = 0;
  #pragma unroll
  for(int l=0;l<=4;l++){
    #pragma unroll
    for(int m=-l;m<=l;m++){
      int ma = (m < 0) ? -m : m;
      float Nn = (float)sqrt((2*l+1)/(4.0*PI_D)*fact[l-ma]/fact[l+ma]);
      float cs = (ma & 1) ? -1.f : 1.f;
      float v;
      if(m == 0)      v = Nn * P[l][0];
      else if(m > 0)  v = 1.4142135623730951f * Nn * cs * cosf(ma*phi) * P[l][ma];
      else            v = 1.4142135623730951f * Nn * cs * sinf(ma*phi) * P[l][ma];
      Y[idx++] = v;
    }
  }
}

// ---------------- u1: {quadrature G | WW prefold | CSR count} --------------
__global__ __launch_bounds__(256) void k_u1(const float* Wrad, const float* W1,
    const float* W2, const int* nbr, float* ws){
  __shared__ float Ysh[12800];
  int b = blockIdx.x, tid = threadIdx.x;
  if(b < 176){
    for(int pt=tid; pt<512; pt+=256){
      float ct  = GLX[pt >> 5];
      float phi = (float)((pt & 31) * (2.0*PI_D/32.0));
      float Y[25];
      real_sph25(ct, phi, Y);
      #pragma unroll
      for(int i=0;i<25;i++) Ysh[pt*25 + i] = Y[i];
    }
    __syncthreads();
    int idx = b*256 + tid;
    int t = idx >> 3, chunk = idx & 7;
    if(t >= 5625) return;
    int k = t % 25, j = (t/25) % 9, i = t/225;
    double acc = 0.0;
    int g0 = chunk*64;
    #pragma unroll 4
    for(int g=g0; g<g0+64; g++){
      double w = GLW[g >> 5] * (2.0*PI_D/32.0);
      acc += w * (double)Ysh[g*25+i] * (double)Ysh[g*25+j] * (double)Ysh[g*25+k];
    }
    acc += __shfl_xor(acc, 1, 8);
    acc += __shfl_xor(acc, 2, 8);
    acc += __shfl_xor(acc, 4, 8);
    if(chunk == 0){
      if(fabs(acc) < 1e-6) acc = 0.0;
      ws[WS_G + (i*9+j)*25 + k] = (float)acc;
    }
  } else if(b < 271){
    int s = b - 176;
    #pragma unroll
    for(int it=0; it<6; it++){
      int idx = tid + 256*it;
      int w = idx / 768, r = idx % 768;
      int d = r / 256, r2 = r % 256, k = r2 / 16, g = r2 % 16;
      const float* Wsrc = (w == 0) ? W1 : W2;
      float acc = 0.f;
      #pragma unroll
      for(int fp=0; fp<16; fp++)
        acc += Wrad[(s*16+k)*16+fp] * Wsrc[(d*16+fp)*16+g];
      ws[WS_WW + ((size_t)(s*2+w)*16 + g)*48 + d*16 + k] = acc;
    }
  } else {
    int p = (b-271)*256 + tid;
    if(p < NP) atomicAdd((int*)ws + WS_CCNT + nbr[2*p], 1);
  }
}

// shfl-based scan: 2 barriers instead of 20
__global__ __launch_bounds__(1024) void k_scan(float* ws){
  __shared__ int wsum[17];
  int t = threadIdx.x;
  const int* cnt = (const int*)ws + WS_CCNT;
  int v0 = cnt[4*t], v1 = cnt[4*t+1], v2 = cnt[4*t+2], v3 = cnt[4*t+3];
  int s = v0+v1+v2+v3;
  int lane = t & 63, w = t >> 6;
  int x = s;
  #pragma unroll
  for(int o=1;o<64;o<<=1){
    int y = __shfl_up(x, o);
    if(lane >= o) x += y;
  }
  if(lane == 63) wsum[w] = x;
  __syncthreads();
  if(t == 0){
    int run = 0;
    #pragma unroll
    for(int i=0;i<16;i++){ int tmp = wsum[i]; wsum[i] = run; run += tmp; }
    wsum[16] = run;
  }
  __syncthreads();
  int base = wsum[w] + x - s;   // exclusive prefix of this thread's 4-group
  int* offp = (int*)ws + WS_COFF;
  int* cur  = (int*)ws + WS_CCUR;
  offp[4*t]   = base;          cur[4*t]   = base;
  offp[4*t+1] = base+v0;       cur[4*t+1] = base+v0;
  offp[4*t+2] = base+v0+v1;    cur[4*t+2] = base+v0+v1;
  offp[4*t+3] = base+v0+v1+v2; cur[4*t+3] = base+v0+v1+v2;
  if(t == 1023) offp[4096] = wsum[16];
}

// ---------------- u2: {Gaunt lists (block 0) | fused fill+pair} ------------
__global__ __launch_bounds__(256) void k_u2(const float* disp, const int* nbr, float* ws){
  __shared__ float Gsh[5632];
  __shared__ int cA[25], cT[9], cA9[25], oA[26], oT[10], oA9[26];
  if(blockIdx.x == 0){
    int t = threadIdx.x;
    for(int i=t; i<5625; i+=256) Gsh[i] = ws[WS_G + i];
    __syncthreads();
    const float* G = Gsh;
    if(t < 25){
      int c=0, c9=0;
      for(int i=0;i<25;i++) for(int j=0;j<9;j++) if(G[(i*9+j)*25+t] != 0.f){ c++; if(i<9) c9++; }
      cA[t]=c; cA9[t]=c9;
    }
    if(t < 9){ int c=0; for(int i=0;i<9;i++) for(int j=0;j<9;j++) if(G[(i*9+j)*25+t] != 0.f) c++; cT[t]=c; }
    __syncthreads();
    if(t == 0){
      int s=0; for(int k=0;k<25;k++){ oA[k]=s; s+=cA[k]; } oA[25]=s;
      ((int*)ws)[WS_NATT] = s;
      s=0; for(int k=0;k<25;k++){ oA9[k]=s; s+=cA9[k]; } oA9[25]=s;
      s=0; for(int k=0;k<9;k++){ oT[k]=s; s+=cT[k]; } oT[9]=s;
    }
    __syncthreads();
    float* attw = ws + WS_ATTW;  int* attij = (int*)ws + WS_ATTIJ;
    float* attw9 = ws + WS_ATTW9; int* attij9 = (int*)ws + WS_ATTIJ9;
    int* aofs  = (int*)ws + WS_AOFS;
    int* aofs9 = (int*)ws + WS_AOFS9;
    if(t < 26){ aofs[t] = oA[t] < 1024 ? oA[t] : 1024; aofs9[t] = oA9[t] < 512 ? oA9[t] : 512; }
    if(t < 25){
      int pos = oA[t], pos9 = oA9[t];
      for(int i=0;i<25;i++) for(int j=0;j<9;j++){
        float w = G[(i*9+j)*25+t];
        if(w != 0.f){
          if(pos < 1024){ attw[pos]=w; attij[pos] = i | (j<<5) | (t<<9); pos++; }
          if(i < 9 && pos9 < 512){ attw9[pos9]=w; attij9[pos9] = i | (j<<5) | (t<<9); pos9++; }
        }
      }
    }
    float* tdw = ws + WS_TDW; int* tdij = (int*)ws + WS_TDIJ; int* tdofs = (int*)ws + WS_TDOFS;
    if(t < 9){
      int pos = oT[t];
      for(int i=0;i<9;i++) for(int j=0;j<9;j++){
        float w = G[(i*9+j)*25+t];
        if(w != 0.f && pos < 512){
          int li = (i==0)?0:(i<4)?1:2, lj = (j==0)?0:(j<4)?1:2;
          tdw[pos]=w; tdij[pos] = i | (j<<5) | (li<<10) | (lj<<12); pos++;
        }
      }
      tdofs[t] = oT[t];
      if(t == 0) tdofs[9] = oT[9];
    }
  } else {
    int p = (blockIdx.x-1)*256 + threadIdx.x;
    if(p >= NP) return;
    int d = nbr[2*p], s = nbr[2*p+1];
    int sp = atomicAdd((int*)ws + WS_CCUR + d, 1);
    ((int*)ws)[WS_DS + 2*sp]     = d;
    ((int*)ws)[WS_DS + 2*sp + 1] = s;
    float dx = disp[3*p], dy = disp[3*p+1], dz = disp[3*p+2];
    float r = sqrtf(dx*dx + dy*dy + dz*dz);
    float inv = 1.f / fmaxf(r, 1e-9f);
    float ux = dx*inv, uy = dy*inv, uz = dz*inv;
    float sh[9];
    sh[0] = 0.28209479177387814f;
    sh[1] = 0.4886025119029199f * uy;
    sh[2] = 0.4886025119029199f * uz;
    sh[3] = 0.4886025119029199f * ux;
    sh[4] = 1.0925484305920792f * ux*uy;
    sh[5] = 1.0925484305920792f * uy*uz;
    sh[6] = 0.31539156525252005f * (3.f*uz*uz - 1.f);
    sh[7] = 1.0925484305920792f * ux*uz;
    sh[8] = 0.5462742152960396f * (ux*ux - uy*uy);
    #pragma unroll
    for(int i=0;i<9;i++) ws[WS_SH + sp*9 + i] = scrub(sh[i]);
    float mask = (r < 5.f) ? 1.f : 0.f;
    float rbv[16];
    #pragma unroll
    for(int k=1;k<=16;k++){
      float x  = (float)k * r * 0.2f;
      float px = 3.14159265358979323846f * x;
      float s2 = (px < 1e-6f) ? 1.f : (sinf(px)/px);
      rbv[k-1] = scrub(s2 * mask);
    }
    float4* rb4 = (float4*)(ws + WS_RB + sp*16);
    #pragma unroll
    for(int c=0;c<4;c++) rb4[c] = make_float4(rbv[4*c], rbv[4*c+1], rbv[4*c+2], rbv[4*c+3]);
  }
}

// ---------------- TD phase (sorted-index reads, W3 staged in LDS) ----------
__global__ __launch_bounds__(256) void k_td(const int* aZ, const float* W3, float* ws){
  __shared__ float sh_s[16][9];
  __shared__ float S_s[16][88];
  __shared__ float tp_s[16][9][16];
  __shared__ float w3_sh[768];
  int tid = threadIdx.x, pl = tid >> 4, g = tid & 15;
  int sp = blockIdx.x*16 + pl;
  int src = ((const int*)ws)[WS_DS + 2*sp + 1];
  int Zj = aZ[src];
  {
    float4* S4 = (float4*)&S_s[0][0];
    for(int t0=tid; t0<352; t0+=256) S4[t0] = make_float4(0.f,0.f,0.f,0.f);
  }
  for(int t0=tid; t0<768; t0+=256) w3_sh[t0] = W3[t0];
  if(g < 9) sh_s[pl][g] = ws[WS_SH + sp*9 + g];
  float rb[16];
  {
    const float4* rb4 = (const float4*)(ws + WS_RB + sp*16);
    #pragma unroll
    for(int c=0;c<4;c++){
      float4 r = rb4[c];
      rb[4*c]=r.x; rb[4*c+1]=r.y; rb[4*c+2]=r.z; rb[4*c+3]=r.w;
    }
  }
  float A1[3], A2[3];
  {
    const float4* w1 = (const float4*)(ws + WS_WW + ((size_t)(Zj*2+0)*16+g)*48);
    const float4* w2 = (const float4*)(ws + WS_WW + ((size_t)(Zj*2+1)*16+g)*48);
    #pragma unroll
    for(int d=0; d<3; d++){
      float a1 = 0.f, a2 = 0.f;
      #pragma unroll
      for(int c=0;c<4;c++){
        float4 x1 = w1[d*4+c], x2 = w2[d*4+c];
        a1 += x1.x*rb[4*c] + x1.y*rb[4*c+1] + x1.z*rb[4*c+2] + x1.w*rb[4*c+3];
        a2 += x2.x*rb[4*c] + x2.y*rb[4*c+1] + x2.z*rb[4*c+2] + x2.w*rb[4*c+3];
      }
      A1[d] = a1; A2[d] = a2;
    }
  }
  __syncthreads();
  if(g < 9){
    const float* tdw = ws + WS_TDW;
    const int* tdij  = (const int*)ws + WS_TDIJ;
    const int* tdofs = (const int*)ws + WS_TDOFS;
    int e1 = tdofs[g+1];
    for(int e=tdofs[g]; e<e1; e++){
      float w = tdw[e]; int meta = tdij[e];
      int i = meta & 31, j = (meta>>5) & 15, li = (meta>>10) & 3, lj = (meta>>12) & 3;
      S_s[pl][g*9 + li*3 + lj] += w * sh_s[pl][i] * sh_s[pl][j];
    }
  }
  __syncthreads();
  float AA[9];
  #pragma unroll
  for(int li=0;li<3;li++)
    #pragma unroll
    for(int lj=0;lj<3;lj++) AA[li*3+lj] = A1[li]*A2[lj];
  #pragma unroll
  for(int k=0;k<9;k++){
    float tpv = 0.f;
    #pragma unroll
    for(int c=0;c<9;c++) tpv += S_s[pl][k*9+c] * AA[c];
    tp_s[pl][k][g] = tpv;
  }
  __syncthreads();
  float acc9[9];
  #pragma unroll
  for(int k=0;k<9;k++){
    int d = (k==0)?0:(k<4)?1:2;
    const float4* t4 = (const float4*)&tp_s[pl][k][0];
    float acc = 0.f;
    #pragma unroll
    for(int c=0;c<4;c++){
      float4 t = t4[c];
      acc += t.x*w3_sh[(d*16+4*c)*16+g]   + t.y*w3_sh[(d*16+4*c+1)*16+g]
           + t.z*w3_sh[(d*16+4*c+2)*16+g] + t.w*w3_sh[(d*16+4*c+3)*16+g];
    }
    acc9[k] = scrub(acc);
  }
  f16* ptd = (f16*)(ws + WS_PVF) + (size_t)sp*256 + g*16;
  U4H u0, u1;
  #pragma unroll
  for(int j=0;j<8;j++) u0.h[j] = (f16)acc9[j];
  u1.h[0] = (f16)acc9[8];
  #pragma unroll
  for(int j=1;j<8;j++) u1.h[j] = (f16)0.f;
  *(uint4*)(ptd)     = u0.u;
  *(uint4*)(ptd + 8) = u1.u;
}

// ---------------- fused TD gather + layer-1 QKV (NL=3) ---------------------
// NOTE: rows 9..15 of q/k/v are ZERO-FILLED (k_att<9> reads i<16 as uint4).
__global__ __launch_bounds__(256) void k_tdq(const float* Wq, const float* Wk,
                                             const float* Wv, float* ws){
  __shared__ float xsh[4][144];
  __shared__ float wq_sh[768], wk_sh[768], wv_sh[768];
  int tid = threadIdx.x, al = tid >> 6, lane = tid & 63;
  int a = blockIdx.x*4 + al;
  for(int t=tid; t<768; t+=256){ wq_sh[t]=Wq[t]; wk_sh[t]=Wk[t]; wv_sh[t]=Wv[t]; }
  const int* coff = (const int*)ws + WS_COFF;
  int off0 = coff[a], n = coff[a+1] - off0;
  const f16* base = (const f16*)(ws + WS_PVF);
  float acc[8] = {0,0,0,0,0,0,0,0}, acc2[8] = {0,0,0,0,0,0,0,0};
  if(lane < 32){
    int t = 0;
    for(; t+1 < n; t += 2){
      U4H u0; u0.u = *(const uint4*)(base + (size_t)(off0+t  )*256 + lane*8);
      U4H u1; u1.u = *(const uint4*)(base + (size_t)(off0+t+1)*256 + lane*8);
      #pragma unroll
      for(int j=0;j<8;j++){ acc[j] += (float)u0.h[j]; acc2[j] += (float)u1.h[j]; }
    }
    if(t < n){
      U4H u0; u0.u = *(const uint4*)(base + (size_t)(off0+t)*256 + lane*8);
      #pragma unroll
      for(int j=0;j<8;j++) acc[j] += (float)u0.h[j];
    }
  }
  float invn = 1.f / fmaxf((float)n, 1.f);
  if(lane < 32){
    int gg = lane >> 1;
    #pragma unroll
    for(int j=0;j<8;j++){
      int k = (lane & 1)*8 + j;
      if(k < 9) xsh[al][k*16 + gg] = scrub((acc[j]+acc2[j])*invn);
    }
  }
  __syncthreads();
  int g = lane & 15, q4 = lane >> 4;
  f16* qt = (f16*)(ws + WS_XQ) + (size_t)a*800 + g*32;
  f16* kt = (f16*)(ws + WS_XK) + (size_t)a*800 + g*32;
  f16* vt = (f16*)(ws + WS_XV) + (size_t)a*800 + g*32;
  for(int i=q4; i<16; i+=4){
    if(i < 9){
      int l = (i==0)?0:(i<4)?1:2;
      float q=0.f, k2=0.f, v2=0.f;
      #pragma unroll
      for(int f2=0;f2<16;f2++){
        float xv = xsh[al][i*16+f2];
        q  += xv*wq_sh[(l*16+f2)*16+g];
        k2 += xv*wk_sh[(l*16+f2)*16+g];
        v2 += xv*wv_sh[(l*16+f2)*16+g];
      }
      qt[i] = (f16)q; kt[i] = (f16)k2; vt[i] = (f16)v2;
    } else {
      qt[i] = (f16)0.f; kt[i] = (f16)0.f; vt[i] = (f16)0.f;
    }
  }
}

// ---------------- merged attention (r12-best: 16 lanes/pair, single chain) -
template<int NI>
__global__ __launch_bounds__(128) void k_att(const float* Wb, float* ws){
  constexpr int MROWH = (NI == 9) ? 16 : 32;
  constexpr int PLSTR = (NI == 9) ? 408 : 840;
  __shared__ __align__(16) f16 Ml[8][PLSTR];
  __shared__ float sh_s[8][9];
  __shared__ float wb_sh[256];
  constexpr int NPAIR = NI/2;
  constexpr int TAIL  = NI-1;
  int tid = threadIdx.x, pl = tid >> 4, g = tid & 15;
  int sp = blockIdx.x*8 + pl;
  {
    uint4 z; z.x=0; z.y=0; z.z=0; z.w=0;
    uint4* Mz = (uint4*)&Ml[0][0];
    for(int t0=tid; t0<PLSTR; t0+=128) Mz[t0] = z;
  }
  for(int t0=tid; t0<256; t0+=128) wb_sh[t0] = Wb[t0];
  if(g < 9) sh_s[pl][g] = ws[WS_SH + sp*9 + g];
  __syncthreads();
  {
    const float* attw = ws + (NI==9 ? WS_ATTW9 : WS_ATTW);
    const int* attij  = (const int*)ws + (NI==9 ? WS_ATTIJ9 : WS_ATTIJ);
    const int* aofs   = (const int*)ws + (NI==9 ? WS_AOFS9 : WS_AOFS);
    for(int kr=g; kr<25; kr+=16){
      f16* Mrow = &Ml[pl][kr*MROWH];
      int e = aofs[kr], e1 = aofs[kr+1];
      if(e < e1){
        int meta = attij[e];
        int curi = meta & 31;
        float cur = 0.f;
        for(; e<e1; e++){
          meta = attij[e];
          int i2 = meta & 31;
          if(i2 != curi){ Mrow[curi] = (f16)cur; cur = 0.f; curi = i2; }
          cur += attw[e] * sh_s[pl][(meta>>5) & 15];
        }
        Mrow[curi] = (f16)cur;
      }
    }
  }
  __syncthreads();
  int dst = ((const int*)ws)[WS_DS + 2*sp];
  int src = ((const int*)ws)[WS_DS + 2*sp + 1];
  float q_r[NI];
  {
    const f16* qt = (const f16*)(ws + WS_XQ) + (size_t)dst*800 + g*32;
    #pragma unroll
    for(int c=0;c<NPAIR/4;c++){
      U4H u; u.u = *(const uint4*)(qt + c*8);
      #pragma unroll
      for(int j=0;j<8;j++) q_r[c*8+j] = (float)u.h[j];
    }
    q_r[TAIL] = (float)qt[TAIL];
  }
  h2 xk2[NPAIR], xv2[NPAIR];
  float xkT, xvT;
  {
    const f16* kt = (const f16*)(ws + WS_XK) + (size_t)src*800 + g*32;
    const f16* vt = (const f16*)(ws + WS_XV) + (size_t)src*800 + g*32;
    #pragma unroll
    for(int c=0;c<NPAIR/4;c++){
      U4H uk; uk.u = *(const uint4*)(kt + c*8);
      U4H uv; uv.u = *(const uint4*)(vt + c*8);
      #pragma unroll
      for(int j=0;j<4;j++){ xk2[c*4+j] = uk.p[j]; xv2[c*4+j] = uv.p[j]; }
    }
    xkT = (float)kt[TAIL];
    xvT = (float)vt[TAIL];
  }
  float wbf;
  {
    const float4* rb4 = (const float4*)(ws + WS_RB + sp*16);
    float acc = 0.f;
    #pragma unroll
    for(int c=0;c<4;c++){
      float4 r = rb4[c];
      acc += r.x*wb_sh[(4*c)*16+g] + r.y*wb_sh[(4*c+1)*16+g]
           + r.z*wb_sh[(4*c+2)*16+g] + r.w*wb_sh[(4*c+3)*16+g];
    }
    wbf = acc;
  }
  f16* pvf = (f16*)(ws + WS_PVF) + (size_t)sp*400;
  float sacc = 0.f;
  #pragma unroll
  for(int k=0;k<25;k++){
    const uint4* Mq = (const uint4*)&Ml[pl][k*MROWH];
    float mT = (float)Ml[pl][k*MROWH + TAIL];
    float vv = 0.f, kf = 0.f;
    #pragma unroll
    for(int c=0;c<NPAIR/4;c++){
      U4H u; u.u = Mq[c];
      #pragma unroll
      for(int j=0;j<4;j++){
        vv = fdot2(u.p[j], xv2[c*4+j], vv);
        if(k < NI) kf = fdot2(u.p[j], xk2[c*4+j], kf);
      }
    }
    vv += mT * xvT;
    if(k < NI){
      kf += mT * xkT;
      sacc += q_r[k]*kf;
    }
    pvf[k*16 + g] = (f16)scrub(wbf*vv);
  }
  float sl = sacc;
  #pragma unroll
  for(int off=1; off<16; off<<=1) sl += __shfl_xor(sl, off, 16);
  if(g == 0) ws[WS_S + sp] = scrub(sl * 0.05f);   // / sqrt(25*16)
}

// ---------------- fused softmax-gather + output pdense (+QKV next / final) -
template<bool FINAL>
__global__ __launch_bounds__(256) void k_aggo(const float* Wo, const float* bo,
    const int* aZ, const float* emb, const float* Wemb, const float* bemb,
    const float* Wq, const float* Wk, const float* Wv, float* ws, float* out){
  __shared__ float xsh[4][400];
  __shared__ float esh[4][64];
  __shared__ float wo_sh[1280];
  __shared__ float wq_sh[FINAL?4:1280], wk_sh[FINAL?4:1280], wv_sh[FINAL?4:1280];
  __shared__ float osh[FINAL?4:1600];
  int tid = threadIdx.x, al = tid >> 6, lane = tid & 63;
  int a = blockIdx.x*4 + al;
  for(int t=tid; t<1280; t+=256){
    wo_sh[t] = Wo[t];
    if(!FINAL){ wq_sh[t]=Wq[t]; wk_sh[t]=Wk[t]; wv_sh[t]=Wv[t]; }
  }
  const int* coff = (const int*)ws + WS_COFF;
  int off0 = coff[a], n = coff[a+1] - off0;
  float mx = -1e30f;
  for(int t=lane; t<n; t+=64) mx = fmaxf(mx, ws[WS_S + off0 + t]);
  #pragma unroll
  for(int off=1; off<64; off<<=1) mx = fmaxf(mx, __shfl_xor(mx, off));
  float den = 0.f;
  for(int t=lane; t<n; t+=64){
    float e = expf(fminf(ws[WS_S + off0 + t] - mx, 0.f));
    if(t < 64) esh[al][t] = e;      // cache for gather (t==lane on 1st iter)
    den += e;
  }
  #pragma unroll
  for(int off=1; off<64; off<<=1) den += __shfl_xor(den, off);
  float inv_den = 1.f / (den + 1e-9f);
  __syncthreads();                   // publish esh (uniform barrier)
  float acc[8] = {0,0,0,0,0,0,0,0}, acc2[8] = {0,0,0,0,0,0,0,0};
  const f16* base = (const f16*)(ws + WS_PVF);
  int t = 0;
  for(; t+1 < n; t += 2){
    float a0 = (t   < 64 ? esh[al][t]   : expf(fminf(ws[WS_S+off0+t  ]-mx,0.f))) * inv_den;
    float a1 = (t+1 < 64 ? esh[al][t+1] : expf(fminf(ws[WS_S+off0+t+1]-mx,0.f))) * inv_den;
    if(lane < 50){
      U4H u0; u0.u = *(const uint4*)(base + (size_t)(off0+t  )*400 + lane*8);
      U4H u1; u1.u = *(const uint4*)(base + (size_t)(off0+t+1)*400 + lane*8);
      #pragma unroll
      for(int j=0;j<8;j++){ acc[j] += a0*(float)u0.h[j]; acc2[j] += a1*(float)u1.h[j]; }
    }
  }
  if(t < n){
    float a0 = (t < 64 ? esh[al][t] : expf(fminf(ws[WS_S+off0+t]-mx,0.f))) * inv_den;
    if(lane < 50){
      U4H u0; u0.u = *(const uint4*)(base + (size_t)(off0+t)*400 + lane*8);
      #pragma unroll
      for(int j=0;j<8;j++) acc[j] += a0*(float)u0.h[j];
    }
  }
  if(lane < 50){
    #pragma unroll
    for(int j=0;j<8;j++) xsh[al][lane*8 + j] = scrub(acc[j] + acc2[j]);   // flat = k*16+g
  }
  __syncthreads();
  int g = lane & 15, q4 = lane >> 4;
  for(int i=q4; i<25; i+=4){
    int l = (i==0)?0:(i<4)?1:(i<9)?2:(i<16)?3:4;
    float accv = 0.f;
    #pragma unroll
    for(int f2=0;f2<16;f2++) accv += xsh[al][i*16+f2]*wo_sh[(l*16+f2)*16+g];
    if(i == 0){
      accv += bo[g];
      if(FINAL){
        int Z = aZ[a];
        float res = bemb[g];
        #pragma unroll
        for(int e2=0;e2<32;e2++) res += emb[Z*32+e2]*Wemb[e2*16+g];
        accv += res;
      }
    }
    if(FINAL) out[a*400 + i*16 + g] = scrub(accv);
    else      osh[al*400 + i*16 + g] = scrub(accv);
  }
  if(!FINAL){
    __syncthreads();
    f16* qt = (f16*)(ws + WS_XQ) + (size_t)a*800 + g*32;
    f16* kt = (f16*)(ws + WS_XK) + (size_t)a*800 + g*32;
    f16* vt = (f16*)(ws + WS_XV) + (size_t)a*800 + g*32;
    for(int i=q4; i<25; i+=4){
      int l = (i==0)?0:(i<4)?1:(i<9)?2:(i<16)?3:4;
      float q=0.f, k2=0.f, v2=0.f;
      #pragma unroll
      for(int f2=0;f2<16;f2++){
        float xv = osh[al*400 + i*16 + f2];
        q  += xv*wq_sh[(l*16+f2)*16+g];
        k2 += xv*wk_sh[(l*16+f2)*16+g];
        v2 += xv*wv_sh[(l*16+f2)*16+g];
      }
      qt[i] = (f16)q; kt[i] = (f16)k2; vt[i] = (f16)v2;
    }
  }
}

extern "C" void kernel_launch(void* const* d_in, const int* in_sizes, int n_in,
                              void* d_out, int out_size, void* d_ws, size_t ws_size,
                              hipStream_t stream){
  (void)in_sizes; (void)n_in; (void)out_size;
  if(ws_size < (size_t)WS_END * sizeof(float)) return;
  float* ws = (float*)d_ws;
  const int* aZ  = (const int*)d_in[0];
  const int* nbr = (const int*)d_in[1];
  const float* disp = (const float*)d_in[2];
  const float* Wrad = (const float*)d_in[3];
  const float* emb  = (const float*)d_in[4];
  const float* Wemb = (const float*)d_in[5];
  const float* bemb = (const float*)d_in[6];
  const float* W1   = (const float*)d_in[7];
  const float* W2   = (const float*)d_in[8];
  const float* W3   = (const float*)d_in[9];
  const float* Wb1 = (const float*)d_in[10]; const float* Wq1 = (const float*)d_in[11];
  const float* Wk1 = (const float*)d_in[12]; const float* Wv1 = (const float*)d_in[13];
  const float* Wo1 = (const float*)d_in[14]; const float* bo1 = (const float*)d_in[15];
  const float* Wb2 = (const float*)d_in[16]; const float* Wq2 = (const float*)d_in[17];
  const float* Wk2 = (const float*)d_in[18]; const float* Wv2 = (const float*)d_in[19];
  const float* Wo2 = (const float*)d_in[20]; const float* bo2 = (const float*)d_in[21];

  hipMemsetAsync(ws + WS_CCNT, 0, NA*sizeof(int), stream);
  k_u1<<<463,256,0,stream>>>(Wrad, W1, W2, nbr, ws);     // G | WW | CSR-count
  k_scan<<<1,1024,0,stream>>>(ws);
  k_u2<<<193,256,0,stream>>>(disp, nbr, ws);             // lists | fill+pair
  k_td<<<3072,256,0,stream>>>(aZ, W3, ws);
  k_tdq<<<1024,256,0,stream>>>(Wq1, Wk1, Wv1, ws);

  k_att<9><<<6144,128,0,stream>>>(Wb1, ws);
  k_aggo<false><<<1024,256,0,stream>>>(Wo1, bo1, aZ, emb, Wemb, bemb,
                                       Wq2, Wk2, Wv2, ws, nullptr);
  k_att<25><<<6144,128,0,stream>>>(Wb2, ws);
  k_aggo<true><<<1024,256,0,stream>>>(Wo2, bo2, aZ, emb, Wemb, bemb,
                                      nullptr, nullptr, nullptr, ws, (float*)d_out);
}

// Round 21
// 373.923 us; speedup vs baseline: 1.0448x; 1.0414x over previous
//
#include <hip/hip_runtime.h>
#include <hip/hip_bf16.h>

#define NA 4096
#define NP 49152

typedef _Float16 f16;
typedef _Float16 h2 __attribute__((ext_vector_type(2)));
union U4H { uint4 u; f16 h[8]; h2 p[4]; };

__device__ __forceinline__ float fdot2(h2 a, h2 b, float c){
#if __has_builtin(__builtin_amdgcn_fdot2)
  return __builtin_amdgcn_fdot2(a, b, c, false);
#else
  return c + (float)a.x*(float)b.x + (float)a.y*(float)b.y;
#endif
}

// ---------------- ws layout (float-element offsets) ----------------
constexpr int WS_AOFS9 = 64;                   // 32 ints
constexpr int WS_ATTW9 = 128;                  // 512 floats
constexpr int WS_ATTIJ9= WS_ATTW9 + 512;       // 512 ints
constexpr int WS_G     = 12800;                // 5625 Gaunt tensor
constexpr int WS_NATT  = WS_G + 5632;          // int
constexpr int WS_ATTW  = WS_NATT + 8;          // 1024 floats
constexpr int WS_ATTIJ = WS_ATTW + 1024;       // 1024 ints (sorted by k, i-major)
constexpr int WS_TDOFS = WS_ATTIJ + 1024;      // 16 ints
constexpr int WS_TDW   = WS_TDOFS + 16;        // 512 floats
constexpr int WS_TDIJ  = WS_TDW + 512;         // 512 ints
constexpr int WS_AOFS  = WS_TDIJ + 512;        // 32 ints
constexpr int WS_SH    = WS_AOFS + 32;         // NP*9  (SORTED index)
constexpr int WS_RB    = WS_SH + NP*9;         // NP*16 (SORTED index)
constexpr int WS_S     = WS_RB + NP*16;        // NP scores (sorted index)
constexpr int WS_CCNT  = WS_S + NP;            // NA ints
constexpr int WS_COFF  = WS_CCNT + NA;         // NA+1 ints
constexpr int WS_CCUR  = WS_COFF + NA + 8;     // NA ints
constexpr int WS_CLST  = WS_CCUR + NA;         // (unused, kept for layout)
constexpr int WS_XQ    = WS_CLST + NP;         // f16 transposed q (NA*800 halves)
constexpr int WS_XK    = WS_XQ + NA*400;
constexpr int WS_XV    = WS_XK + NA*400;
constexpr int WS_PVF   = WS_XV + NA*400;       // f16: td [sp][g][16]; att [sp][400h]
constexpr int WS_WW    = WS_PVF + NP*128;      // 145920 floats (dead after k_td)
constexpr int WS_PVFE  = WS_PVF + NP*256;
constexpr int WS_DS    = WS_PVFE;              // 2*NP ints: [2*sp]=dst, [2*sp+1]=src
constexpr long long WS_END = (long long)WS_DS + 2*NP + 16;  // ~76 MB

__device__ const float  GLX[16] = {
  -0.98940093499164993f, -0.94457502307323258f, -0.86563120238783174f, -0.75540440835500303f,
  -0.61787624440264375f, -0.45801677765722739f, -0.28160355077925891f, -0.09501250983763744f,
   0.09501250983763744f,  0.28160355077925891f,  0.45801677765722739f,  0.61787624440264375f,
   0.75540440835500303f,  0.86563120238783174f,  0.94457502307323258f,  0.98940093499164993f };
__device__ const double GLW[16] = {
  0.02715245941175409, 0.06225352393864789, 0.09515851168249278, 0.12462897125553387,
  0.14959598881657673, 0.16915651939500254, 0.18260341504492359, 0.18945061045506850,
  0.18945061045506850, 0.18260341504492359, 0.16915651939500254, 0.14959598881657673,
  0.12462897125553387, 0.09515851168249278, 0.06225352393864789, 0.02715245941175409 };

#define PI_D 3.14159265358979323846

__device__ __forceinline__ float scrub(float v){
  if(!(v == v)) return 0.f;
  return fminf(fmaxf(v, -1e30f), 1e30f);
}

__device__ void real_sph25(float ct, float phi, float* Y){
  float st = sqrtf(fmaxf(0.f, 1.f - ct*ct));
  float P[5][5];
  P[0][0] = 1.f;
  #pragma unroll
  for(int m=1;m<=4;m++) P[m][m] = -(2.f*m - 1.f)*st*P[m-1][m-1];
  #pragma unroll
  for(int m=0;m<4;m++) P[m+1][m] = (2.f*m + 1.f)*ct*P[m][m];
  #pragma unroll
  for(int m=0;m<=4;m++){
    #pragma unroll
    for(int l=m+2;l<=4;l++)
      P[l][m] = ((2.f*l - 1.f)*ct*P[l-1][m] - (float)(l+m-1)*P[l-2][m]) / (float)(l-m);
  }
  const double fact[9] = {1,1,2,6,24,120,720,5040,40320};
  int idx = 0;
  #pragma unroll
  for(int l=0;l<=4;l++){
    #pragma unroll
    for(int m=-l;m<=l;m++){
      int ma = (m < 0) ? -m : m;
      float Nn = (float)sqrt((2*l+1)/(4.0*PI_D)*fact[l-ma]/fact[l+ma]);
      float cs = (ma & 1) ? -1.f : 1.f;
      float v;
      if(m == 0)      v = Nn * P[l][0];
      else if(m > 0)  v = 1.4142135623730951f * Nn * cs * cosf(ma*phi) * P[l][ma];
      else            v = 1.4142135623730951f * Nn * cs * sinf(ma*phi) * P[l][ma];
      Y[idx++] = v;
    }
  }
}

// ---------------- u1: {quadrature G | WW prefold | CSR count} --------------
__global__ __launch_bounds__(256) void k_u1(const float* Wrad, const float* W1,
    const float* W2, const int* nbr, float* ws){
  __shared__ float Ysh[12800];
  int b = blockIdx.x, tid = threadIdx.x;
  if(b < 176){
    for(int pt=tid; pt<512; pt+=256){
      float ct  = GLX[pt >> 5];
      float phi = (float)((pt & 31) * (2.0*PI_D/32.0));
      float Y[25];
      real_sph25(ct, phi, Y);
      #pragma unroll
      for(int i=0;i<25;i++) Ysh[pt*25 + i] = Y[i];
    }
    __syncthreads();
    int idx = b*256 + tid;
    int t = idx >> 3, chunk = idx & 7;
    if(t >= 5625) return;
    int k = t % 25, j = (t/25) % 9, i = t/225;
    double acc = 0.0;
    int g0 = chunk*64;
    #pragma unroll 4
    for(int g=g0; g<g0+64; g++){
      double w = GLW[g >> 5] * (2.0*PI_D/32.0);
      acc += w * (double)Ysh[g*25+i] * (double)Ysh[g*25+j] * (double)Ysh[g*25+k];
    }
    acc += __shfl_xor(acc, 1, 8);
    acc += __shfl_xor(acc, 2, 8);
    acc += __shfl_xor(acc, 4, 8);
    if(chunk == 0){
      if(fabs(acc) < 1e-6) acc = 0.0;
      ws[WS_G + (i*9+j)*25 + k] = (float)acc;
    }
  } else if(b < 271){
    int s = b - 176;
    #pragma unroll
    for(int it=0; it<6; it++){
      int idx = tid + 256*it;
      int w = idx / 768, r = idx % 768;
      int d = r / 256, r2 = r % 256, k = r2 / 16, g = r2 % 16;
      const float* Wsrc = (w == 0) ? W1 : W2;
      float acc = 0.f;
      #pragma unroll
      for(int fp=0; fp<16; fp++)
        acc += Wrad[(s*16+k)*16+fp] * Wsrc[(d*16+fp)*16+g];
      ws[WS_WW + ((size_t)(s*2+w)*16 + g)*48 + d*16 + k] = acc;
    }
  } else {
    int p = (b-271)*256 + tid;
    if(p < NP) atomicAdd((int*)ws + WS_CCNT + nbr[2*p], 1);
  }
}

// shfl-based scan: 2 barriers instead of 20
__global__ __launch_bounds__(1024) void k_scan(float* ws){
  __shared__ int wsum[17];
  int t = threadIdx.x;
  const int* cnt = (const int*)ws + WS_CCNT;
  int v0 = cnt[4*t], v1 = cnt[4*t+1], v2 = cnt[4*t+2], v3 = cnt[4*t+3];
  int s = v0+v1+v2+v3;
  int lane = t & 63, w = t >> 6;
  int x = s;
  #pragma unroll
  for(int o=1;o<64;o<<=1){
    int y = __shfl_up(x, o);
    if(lane >= o) x += y;
  }
  if(lane == 63) wsum[w] = x;
  __syncthreads();
  if(t == 0){
    int run = 0;
    #pragma unroll
    for(int i=0;i<16;i++){ int tmp = wsum[i]; wsum[i] = run; run += tmp; }
    wsum[16] = run;
  }
  __syncthreads();
  int base = wsum[w] + x - s;   // exclusive prefix of this thread's 4-group
  int* offp = (int*)ws + WS_COFF;
  int* cur  = (int*)ws + WS_CCUR;
  offp[4*t]   = base;          cur[4*t]   = base;
  offp[4*t+1] = base+v0;       cur[4*t+1] = base+v0;
  offp[4*t+2] = base+v0+v1;    cur[4*t+2] = base+v0+v1;
  offp[4*t+3] = base+v0+v1+v2; cur[4*t+3] = base+v0+v1+v2;
  if(t == 1023) offp[4096] = wsum[16];
}

// ---------------- u2: {Gaunt lists (block 0) | fused fill+pair} ------------
__global__ __launch_bounds__(256) void k_u2(const float* disp, const int* nbr, float* ws){
  __shared__ float Gsh[5632];
  __shared__ int cA[25], cT[9], cA9[25], oA[26], oT[10], oA9[26];
  if(blockIdx.x == 0){
    int t = threadIdx.x;
    for(int i=t; i<5625; i+=256) Gsh[i] = ws[WS_G + i];
    __syncthreads();
    const float* G = Gsh;
    if(t < 25){
      int c=0, c9=0;
      for(int i=0;i<25;i++) for(int j=0;j<9;j++) if(G[(i*9+j)*25+t] != 0.f){ c++; if(i<9) c9++; }
      cA[t]=c; cA9[t]=c9;
    }
    if(t < 9){ int c=0; for(int i=0;i<9;i++) for(int j=0;j<9;j++) if(G[(i*9+j)*25+t] != 0.f) c++; cT[t]=c; }
    __syncthreads();
    if(t == 0){
      int s=0; for(int k=0;k<25;k++){ oA[k]=s; s+=cA[k]; } oA[25]=s;
      ((int*)ws)[WS_NATT] = s;
      s=0; for(int k=0;k<25;k++){ oA9[k]=s; s+=cA9[k]; } oA9[25]=s;
      s=0; for(int k=0;k<9;k++){ oT[k]=s; s+=cT[k]; } oT[9]=s;
    }
    __syncthreads();
    float* attw = ws + WS_ATTW;  int* attij = (int*)ws + WS_ATTIJ;
    float* attw9 = ws + WS_ATTW9; int* attij9 = (int*)ws + WS_ATTIJ9;
    int* aofs  = (int*)ws + WS_AOFS;
    int* aofs9 = (int*)ws + WS_AOFS9;
    if(t < 26){ aofs[t] = oA[t] < 1024 ? oA[t] : 1024; aofs9[t] = oA9[t] < 512 ? oA9[t] : 512; }
    if(t < 25){
      int pos = oA[t], pos9 = oA9[t];
      for(int i=0;i<25;i++) for(int j=0;j<9;j++){
        float w = G[(i*9+j)*25+t];
        if(w != 0.f){
          if(pos < 1024){ attw[pos]=w; attij[pos] = i | (j<<5) | (t<<9); pos++; }
          if(i < 9 && pos9 < 512){ attw9[pos9]=w; attij9[pos9] = i | (j<<5) | (t<<9); pos9++; }
        }
      }
    }
    float* tdw = ws + WS_TDW; int* tdij = (int*)ws + WS_TDIJ; int* tdofs = (int*)ws + WS_TDOFS;
    if(t < 9){
      int pos = oT[t];
      for(int i=0;i<9;i++) for(int j=0;j<9;j++){
        float w = G[(i*9+j)*25+t];
        if(w != 0.f && pos < 512){
          int li = (i==0)?0:(i<4)?1:2, lj = (j==0)?0:(j<4)?1:2;
          tdw[pos]=w; tdij[pos] = i | (j<<5) | (li<<10) | (lj<<12); pos++;
        }
      }
      tdofs[t] = oT[t];
      if(t == 0) tdofs[9] = oT[9];
    }
  } else {
    int p = (blockIdx.x-1)*256 + threadIdx.x;
    if(p >= NP) return;
    int d = nbr[2*p], s = nbr[2*p+1];
    int sp = atomicAdd((int*)ws + WS_CCUR + d, 1);
    ((int*)ws)[WS_DS + 2*sp]     = d;
    ((int*)ws)[WS_DS + 2*sp + 1] = s;
    float dx = disp[3*p], dy = disp[3*p+1], dz = disp[3*p+2];
    float r = sqrtf(dx*dx + dy*dy + dz*dz);
    float inv = 1.f / fmaxf(r, 1e-9f);
    float ux = dx*inv, uy = dy*inv, uz = dz*inv;
    float sh[9];
    sh[0] = 0.28209479177387814f;
    sh[1] = 0.4886025119029199f * uy;
    sh[2] = 0.4886025119029199f * uz;
    sh[3] = 0.4886025119029199f * ux;
    sh[4] = 1.0925484305920792f * ux*uy;
    sh[5] = 1.0925484305920792f * uy*uz;
    sh[6] = 0.31539156525252005f * (3.f*uz*uz - 1.f);
    sh[7] = 1.0925484305920792f * ux*uz;
    sh[8] = 0.5462742152960396f * (ux*ux - uy*uy);
    #pragma unroll
    for(int i=0;i<9;i++) ws[WS_SH + sp*9 + i] = scrub(sh[i]);
    float mask = (r < 5.f) ? 1.f : 0.f;
    float rbv[16];
    #pragma unroll
    for(int k=1;k<=16;k++){
      float x  = (float)k * r * 0.2f;
      float px = 3.14159265358979323846f * x;
      float s2 = (px < 1e-6f) ? 1.f : (sinf(px)/px);
      rbv[k-1] = scrub(s2 * mask);
    }
    float4* rb4 = (float4*)(ws + WS_RB + sp*16);
    #pragma unroll
    for(int c=0;c<4;c++) rb4[c] = make_float4(rbv[4*c], rbv[4*c+1], rbv[4*c+2], rbv[4*c+3]);
  }
}

// ---------------- TD phase (r18 form: W3 in registers) ----------------
__global__ __launch_bounds__(256) void k_td(const int* aZ, const float* W3, float* ws){
  __shared__ float sh_s[16][9];
  __shared__ float S_s[16][88];
  __shared__ float tp_s[16][9][16];
  int tid = threadIdx.x, pl = tid >> 4, g = tid & 15;
  int sp = blockIdx.x*16 + pl;
  int src = ((const int*)ws)[WS_DS + 2*sp + 1];
  int Zj = aZ[src];
  {
    float4* S4 = (float4*)&S_s[0][0];
    for(int t0=tid; t0<352; t0+=256) S4[t0] = make_float4(0.f,0.f,0.f,0.f);
  }
  if(g < 9) sh_s[pl][g] = ws[WS_SH + sp*9 + g];
  float rb[16];
  {
    const float4* rb4 = (const float4*)(ws + WS_RB + sp*16);
    #pragma unroll
    for(int c=0;c<4;c++){
      float4 r = rb4[c];
      rb[4*c]=r.x; rb[4*c+1]=r.y; rb[4*c+2]=r.z; rb[4*c+3]=r.w;
    }
  }
  float A1[3], A2[3];
  {
    const float4* w1 = (const float4*)(ws + WS_WW + ((size_t)(Zj*2+0)*16+g)*48);
    const float4* w2 = (const float4*)(ws + WS_WW + ((size_t)(Zj*2+1)*16+g)*48);
    #pragma unroll
    for(int d=0; d<3; d++){
      float a1 = 0.f, a2 = 0.f;
      #pragma unroll
      for(int c=0;c<4;c++){
        float4 x1 = w1[d*4+c], x2 = w2[d*4+c];
        a1 += x1.x*rb[4*c] + x1.y*rb[4*c+1] + x1.z*rb[4*c+2] + x1.w*rb[4*c+3];
        a2 += x2.x*rb[4*c] + x2.y*rb[4*c+1] + x2.z*rb[4*c+2] + x2.w*rb[4*c+3];
      }
      A1[d] = a1; A2[d] = a2;
    }
  }
  __syncthreads();
  if(g < 9){
    const float* tdw = ws + WS_TDW;
    const int* tdij  = (const int*)ws + WS_TDIJ;
    const int* tdofs = (const int*)ws + WS_TDOFS;
    int e1 = tdofs[g+1];
    for(int e=tdofs[g]; e<e1; e++){
      float w = tdw[e]; int meta = tdij[e];
      int i = meta & 31, j = (meta>>5) & 15, li = (meta>>10) & 3, lj = (meta>>12) & 3;
      S_s[pl][g*9 + li*3 + lj] += w * sh_s[pl][i] * sh_s[pl][j];
    }
  }
  __syncthreads();
  float AA[9];
  #pragma unroll
  for(int li=0;li<3;li++)
    #pragma unroll
    for(int lj=0;lj<3;lj++) AA[li*3+lj] = A1[li]*A2[lj];
  #pragma unroll
  for(int k=0;k<9;k++){
    float tpv = 0.f;
    #pragma unroll
    for(int c=0;c<9;c++) tpv += S_s[pl][k*9+c] * AA[c];
    tp_s[pl][k][g] = tpv;
  }
  __syncthreads();
  float w3r[48];
  #pragma unroll
  for(int d=0;d<3;d++)
    #pragma unroll
    for(int f2=0;f2<16;f2++) w3r[d*16+f2] = W3[(d*16+f2)*16+g];
  float acc9[9];
  #pragma unroll
  for(int k=0;k<9;k++){
    int d = (k==0)?0:(k<4)?1:2;
    const float4* t4 = (const float4*)&tp_s[pl][k][0];
    float acc = 0.f;
    #pragma unroll
    for(int c=0;c<4;c++){
      float4 t = t4[c];
      acc += t.x*w3r[d*16+4*c] + t.y*w3r[d*16+4*c+1] + t.z*w3r[d*16+4*c+2] + t.w*w3r[d*16+4*c+3];
    }
    acc9[k] = scrub(acc);
  }
  f16* ptd = (f16*)(ws + WS_PVF) + (size_t)sp*256 + g*16;
  U4H u0, u1;
  #pragma unroll
  for(int j=0;j<8;j++) u0.h[j] = (f16)acc9[j];
  u1.h[0] = (f16)acc9[8];
  #pragma unroll
  for(int j=1;j<8;j++) u1.h[j] = (f16)0.f;
  *(uint4*)(ptd)     = u0.u;
  *(uint4*)(ptd + 8) = u1.u;
}

// ---------------- fused TD gather + layer-1 QKV (r18 form) -----------------
// NOTE: rows 9..15 of q/k/v are ZERO-FILLED (k_att<9> reads i<16 as uint4).
__global__ __launch_bounds__(256) void k_tdq(const float* Wq, const float* Wk,
                                             const float* Wv, float* ws){
  __shared__ float xsh[4][144];
  __shared__ float wq_sh[768], wk_sh[768], wv_sh[768];
  int tid = threadIdx.x, al = tid >> 6, lane = tid & 63;
  int a = blockIdx.x*4 + al;
  for(int t=tid; t<768; t+=256){ wq_sh[t]=Wq[t]; wk_sh[t]=Wk[t]; wv_sh[t]=Wv[t]; }
  const int* coff = (const int*)ws + WS_COFF;
  int off0 = coff[a], n = coff[a+1] - off0;
  const f16* base = (const f16*)(ws + WS_PVF);
  float acc[8] = {0,0,0,0,0,0,0,0};
  if(lane < 32){
    for(int t=0; t<n; t++){
      U4H u; u.u = *(const uint4*)(base + (size_t)(off0+t)*256 + lane*8);
      #pragma unroll
      for(int j=0;j<8;j++) acc[j] += (float)u.h[j];
    }
  }
  float invn = 1.f / fmaxf((float)n, 1.f);
  if(lane < 32){
    int gg = lane >> 1;
    #pragma unroll
    for(int j=0;j<8;j++){
      int k = (lane & 1)*8 + j;
      if(k < 9) xsh[al][k*16 + gg] = scrub(acc[j]*invn);
    }
  }
  __syncthreads();
  int g = lane & 15, q4 = lane >> 4;
  f16* qt = (f16*)(ws + WS_XQ) + (size_t)a*800 + g*32;
  f16* kt = (f16*)(ws + WS_XK) + (size_t)a*800 + g*32;
  f16* vt = (f16*)(ws + WS_XV) + (size_t)a*800 + g*32;
  for(int i=q4; i<16; i+=4){
    if(i < 9){
      int l = (i==0)?0:(i<4)?1:2;
      float q=0.f, k2=0.f, v2=0.f;
      #pragma unroll
      for(int f2=0;f2<16;f2++){
        float xv = xsh[al][i*16+f2];
        q  += xv*wq_sh[(l*16+f2)*16+g];
        k2 += xv*wk_sh[(l*16+f2)*16+g];
        v2 += xv*wv_sh[(l*16+f2)*16+g];
      }
      qt[i] = (f16)q; kt[i] = (f16)k2; vt[i] = (f16)v2;
    } else {
      qt[i] = (f16)0.f; kt[i] = (f16)0.f; vt[i] = (f16)0.f;
    }
  }
}

// ---------------- merged attention (r12-best: 16 lanes/pair, single chain) -
template<int NI>
__global__ __launch_bounds__(128) void k_att(const float* Wb, float* ws){
  constexpr int MROWH = (NI == 9) ? 16 : 32;
  constexpr int PLSTR = (NI == 9) ? 408 : 840;
  __shared__ __align__(16) f16 Ml[8][PLSTR];
  __shared__ float sh_s[8][9];
  __shared__ float wb_sh[256];
  constexpr int NPAIR = NI/2;
  constexpr int TAIL  = NI-1;
  int tid = threadIdx.x, pl = tid >> 4, g = tid & 15;
  int sp = blockIdx.x*8 + pl;
  {
    uint4 z; z.x=0; z.y=0; z.z=0; z.w=0;
    uint4* Mz = (uint4*)&Ml[0][0];
    for(int t0=tid; t0<PLSTR; t0+=128) Mz[t0] = z;
  }
  for(int t0=tid; t0<256; t0+=128) wb_sh[t0] = Wb[t0];
  if(g < 9) sh_s[pl][g] = ws[WS_SH + sp*9 + g];
  __syncthreads();
  {
    const float* attw = ws + (NI==9 ? WS_ATTW9 : WS_ATTW);
    const int* attij  = (const int*)ws + (NI==9 ? WS_ATTIJ9 : WS_ATTIJ);
    const int* aofs   = (const int*)ws + (NI==9 ? WS_AOFS9 : WS_AOFS);
    for(int kr=g; kr<25; kr+=16){
      f16* Mrow = &Ml[pl][kr*MROWH];
      int e = aofs[kr], e1 = aofs[kr+1];
      if(e < e1){
        int meta = attij[e];
        int curi = meta & 31;
        float cur = 0.f;
        for(; e<e1; e++){
          meta = attij[e];
          int i2 = meta & 31;
          if(i2 != curi){ Mrow[curi] = (f16)cur; cur = 0.f; curi = i2; }
          cur += attw[e] * sh_s[pl][(meta>>5) & 15];
        }
        Mrow[curi] = (f16)cur;
      }
    }
  }
  __syncthreads();
  int dst = ((const int*)ws)[WS_DS + 2*sp];
  int src = ((const int*)ws)[WS_DS + 2*sp + 1];
  float q_r[NI];
  {
    const f16* qt = (const f16*)(ws + WS_XQ) + (size_t)dst*800 + g*32;
    #pragma unroll
    for(int c=0;c<NPAIR/4;c++){
      U4H u; u.u = *(const uint4*)(qt + c*8);
      #pragma unroll
      for(int j=0;j<8;j++) q_r[c*8+j] = (float)u.h[j];
    }
    q_r[TAIL] = (float)qt[TAIL];
  }
  h2 xk2[NPAIR], xv2[NPAIR];
  float xkT, xvT;
  {
    const f16* kt = (const f16*)(ws + WS_XK) + (size_t)src*800 + g*32;
    const f16* vt = (const f16*)(ws + WS_XV) + (size_t)src*800 + g*32;
    #pragma unroll
    for(int c=0;c<NPAIR/4;c++){
      U4H uk; uk.u = *(const uint4*)(kt + c*8);
      U4H uv; uv.u = *(const uint4*)(vt + c*8);
      #pragma unroll
      for(int j=0;j<4;j++){ xk2[c*4+j] = uk.p[j]; xv2[c*4+j] = uv.p[j]; }
    }
    xkT = (float)kt[TAIL];
    xvT = (float)vt[TAIL];
  }
  float wbf;
  {
    const float4* rb4 = (const float4*)(ws + WS_RB + sp*16);
    float acc = 0.f;
    #pragma unroll
    for(int c=0;c<4;c++){
      float4 r = rb4[c];
      acc += r.x*wb_sh[(4*c)*16+g] + r.y*wb_sh[(4*c+1)*16+g]
           + r.z*wb_sh[(4*c+2)*16+g] + r.w*wb_sh[(4*c+3)*16+g];
    }
    wbf = acc;
  }
  f16* pvf = (f16*)(ws + WS_PVF) + (size_t)sp*400;
  float sacc = 0.f;
  #pragma unroll
  for(int k=0;k<25;k++){
    const uint4* Mq = (const uint4*)&Ml[pl][k*MROWH];
    float mT = (float)Ml[pl][k*MROWH + TAIL];
    float vv = 0.f, kf = 0.f;
    #pragma unroll
    for(int c=0;c<NPAIR/4;c++){
      U4H u; u.u = Mq[c];
      #pragma unroll
      for(int j=0;j<4;j++){
        vv = fdot2(u.p[j], xv2[c*4+j], vv);
        if(k < NI) kf = fdot2(u.p[j], xk2[c*4+j], kf);
      }
    }
    vv += mT * xvT;
    if(k < NI){
      kf += mT * xkT;
      sacc += q_r[k]*kf;
    }
    pvf[k*16 + g] = (f16)scrub(wbf*vv);
  }
  float sl = sacc;
  #pragma unroll
  for(int off=1; off<16; off<<=1) sl += __shfl_xor(sl, off, 16);
  if(g == 0) ws[WS_S + sp] = scrub(sl * 0.05f);   // / sqrt(25*16)
}

// ---------------- fused softmax-gather + output pdense (+QKV next / final) -
template<bool FINAL>
__global__ __launch_bounds__(256) void k_aggo(const float* Wo, const float* bo,
    const int* aZ, const float* emb, const float* Wemb, const float* bemb,
    const float* Wq, const float* Wk, const float* Wv, float* ws, float* out){
  __shared__ float xsh[4][400];
  __shared__ float esh[4][64];
  __shared__ float wo_sh[1280];
  __shared__ float wq_sh[FINAL?4:1280], wk_sh[FINAL?4:1280], wv_sh[FINAL?4:1280];
  __shared__ float osh[FINAL?4:1600];
  int tid = threadIdx.x, al = tid >> 6, lane = tid & 63;
  int a = blockIdx.x*4 + al;
  for(int t=tid; t<1280; t+=256){
    wo_sh[t] = Wo[t];
    if(!FINAL){ wq_sh[t]=Wq[t]; wk_sh[t]=Wk[t]; wv_sh[t]=Wv[t]; }
  }
  const int* coff = (const int*)ws + WS_COFF;
  int off0 = coff[a], n = coff[a+1] - off0;
  float mx = -1e30f;
  for(int t=lane; t<n; t+=64) mx = fmaxf(mx, ws[WS_S + off0 + t]);
  #pragma unroll
  for(int off=1; off<64; off<<=1) mx = fmaxf(mx, __shfl_xor(mx, off));
  float den = 0.f;
  for(int t=lane; t<n; t+=64){
    float e = expf(fminf(ws[WS_S + off0 + t] - mx, 0.f));
    if(t < 64) esh[al][t] = e;      // cache for gather (t==lane on 1st iter)
    den += e;
  }
  #pragma unroll
  for(int off=1; off<64; off<<=1) den += __shfl_xor(den, off);
  float inv_den = 1.f / (den + 1e-9f);
  __syncthreads();                   // publish esh (uniform barrier)
  float acc[8] = {0,0,0,0,0,0,0,0}, acc2[8] = {0,0,0,0,0,0,0,0};
  const f16* base = (const f16*)(ws + WS_PVF);
  int t = 0;
  for(; t+1 < n; t += 2){
    float a0 = (t   < 64 ? esh[al][t]   : expf(fminf(ws[WS_S+off0+t  ]-mx,0.f))) * inv_den;
    float a1 = (t+1 < 64 ? esh[al][t+1] : expf(fminf(ws[WS_S+off0+t+1]-mx,0.f))) * inv_den;
    if(lane < 50){
      U4H u0; u0.u = *(const uint4*)(base + (size_t)(off0+t  )*400 + lane*8);
      U4H u1; u1.u = *(const uint4*)(base + (size_t)(off0+t+1)*400 + lane*8);
      #pragma unroll
      for(int j=0;j<8;j++){ acc[j] += a0*(float)u0.h[j]; acc2[j] += a1*(float)u1.h[j]; }
    }
  }
  if(t < n){
    float a0 = (t < 64 ? esh[al][t] : expf(fminf(ws[WS_S+off0+t]-mx,0.f))) * inv_den;
    if(lane < 50){
      U4H u0; u0.u = *(const uint4*)(base + (size_t)(off0+t)*400 + lane*8);
      #pragma unroll
      for(int j=0;j<8;j++) acc[j] += a0*(float)u0.h[j];
    }
  }
  if(lane < 50){
    #pragma unroll
    for(int j=0;j<8;j++) xsh[al][lane*8 + j] = scrub(acc[j] + acc2[j]);   // flat = k*16+g
  }
  __syncthreads();
  int g = lane & 15, q4 = lane >> 4;
  for(int i=q4; i<25; i+=4){
    int l = (i==0)?0:(i<4)?1:(i<9)?2:(i<16)?3:4;
    float accv = 0.f;
    #pragma unroll
    for(int f2=0;f2<16;f2++) accv += xsh[al][i*16+f2]*wo_sh[(l*16+f2)*16+g];
    if(i == 0){
      accv += bo[g];
      if(FINAL){
        int Z = aZ[a];
        float res = bemb[g];
        #pragma unroll
        for(int e2=0;e2<32;e2++) res += emb[Z*32+e2]*Wemb[e2*16+g];
        accv += res;
      }
    }
    if(FINAL) out[a*400 + i*16 + g] = scrub(accv);
    else      osh[al*400 + i*16 + g] = scrub(accv);
  }
  if(!FINAL){
    __syncthreads();
    f16* qt = (f16*)(ws + WS_XQ) + (size_t)a*800 + g*32;
    f16* kt = (f16*)(ws + WS_XK) + (size_t)a*800 + g*32;
    f16* vt = (f16*)(ws + WS_XV) + (size_t)a*800 + g*32;
    for(int i=q4; i<25; i+=4){
      int l = (i==0)?0:(i<4)?1:(i<9)?2:(i<16)?3:4;
      float q=0.f, k2=0.f, v2=0.f;
      #pragma unroll
      for(int f2=0;f2<16;f2++){
        float xv = osh[al*400 + i*16 + f2];
        q  += xv*wq_sh[(l*16+f2)*16+g];
        k2 += xv*wk_sh[(l*16+f2)*16+g];
        v2 += xv*wv_sh[(l*16+f2)*16+g];
      }
      qt[i] = (f16)q; kt[i] = (f16)k2; vt[i] = (f16)v2;
    }
  }
}

extern "C" void kernel_launch(void* const* d_in, const int* in_sizes, int n_in,
                              void* d_out, int out_size, void* d_ws, size_t ws_size,
                              hipStream_t stream){
  (void)in_sizes; (void)n_in; (void)out_size;
  if(ws_size < (size_t)WS_END * sizeof(float)) return;
  float* ws = (float*)d_ws;
  const int* aZ  = (const int*)d_in[0];
  const int* nbr = (const int*)d_in[1];
  const float* disp = (const float*)d_in[2];
  const float* Wrad = (const float*)d_in[3];
  const float* emb  = (const float*)d_in[4];
  const float* Wemb = (const float*)d_in[5];
  const float* bemb = (const float*)d_in[6];
  const float* W1   = (const float*)d_in[7];
  const float* W2   = (const float*)d_in[8];
  const float* W3   = (const float*)d_in[9];
  const float* Wb1 = (const float*)d_in[10]; const float* Wq1 = (const float*)d_in[11];
  const float* Wk1 = (const float*)d_in[12]; const float* Wv1 = (const float*)d_in[13];
  const float* Wo1 = (const float*)d_in[14]; const float* bo1 = (const float*)d_in[15];
  const float* Wb2 = (const float*)d_in[16]; const float* Wq2 = (const float*)d_in[17];
  const float* Wk2 = (const float*)d_in[18]; const float* Wv2 = (const float*)d_in[19];
  const float* Wo2 = (const float*)d_in[20]; const float* bo2 = (const float*)d_in[21];

  hipMemsetAsync(ws + WS_CCNT, 0, NA*sizeof(int), stream);
  k_u1<<<463,256,0,stream>>>(Wrad, W1, W2, nbr, ws);     // G | WW | CSR-count
  k_scan<<<1,1024,0,stream>>>(ws);
  k_u2<<<193,256,0,stream>>>(disp, nbr, ws);             // lists | fill+pair
  k_td<<<3072,256,0,stream>>>(aZ, W3, ws);
  k_tdq<<<1024,256,0,stream>>>(Wq1, Wk1, Wv1, ws);

  k_att<9><<<6144,128,0,stream>>>(Wb1, ws);
  k_aggo<false><<<1024,256,0,stream>>>(Wo1, bo1, aZ, emb, Wemb, bemb,
                                       Wq2, Wk2, Wv2, ws, nullptr);
  k_att<25><<<6144,128,0,stream>>>(Wb2, ws);
  k_aggo<true><<<1024,256,0,stream>>>(Wo2, bo2, aZ, emb, Wemb, bemb,
                                      nullptr, nullptr, nullptr, ws, (float*)d_out);
}